// Round 1
// baseline (3578.955 us; speedup 1.0000x reference)
//
#include <hip/hip_runtime.h>
#include <math.h>

#define IN_DIM 74
#define HID 128
#define LSEQ 1000

typedef unsigned int u32;
typedef unsigned short u16;

__device__ __forceinline__ float bf2f(u32 lo16){ return __uint_as_float(lo16 << 16); }
__device__ __forceinline__ u16 f2bf(float f){
  u32 u = __float_as_uint(f);
  u32 r = (u + 0x7fffu + ((u >> 16) & 1u)) >> 16;   // round-nearest-even
  return (u16)r;
}

// ---------- graph branch ----------
__global__ void k_deg_init(float* rs_out, float* rs_in, int N){
  int i = blockIdx.x*256 + threadIdx.x;
  if (i < N){ rs_out[i] = 1.f; rs_in[i] = 1.f; }   // self-loop counts as 1
}
__global__ void k_deg_edge(const int* __restrict__ src, const int* __restrict__ dst,
                           float* rs_out, float* rs_in, int E){
  int e = blockIdx.x*256 + threadIdx.x;
  if (e < E){ atomicAdd(&rs_out[src[e]], 1.f); atomicAdd(&rs_in[dst[e]], 1.f); }
}
__global__ void k_deg_rsqrt(float* rs_out, float* rs_in, int N){
  int i = blockIdx.x*256 + threadIdx.x;
  if (i < N){ rs_out[i] = rsqrtf(rs_out[i]); rs_in[i] = rsqrtf(rs_in[i]); }
}
// h_agg[i] = node_feats[i] * rs_out[i]   (self-loop term)
__global__ void k_init_hagg(const float* __restrict__ nf, const float* __restrict__ rs_out,
                            float* h_agg, int total){
  int idx = blockIdx.x*256 + threadIdx.x;
  if (idx < total) h_agg[idx] = nf[idx] * rs_out[idx / IN_DIM];
}
// h_agg[dst] += nf[src] * rs_out[src]
__global__ void k_edge_scatter(const int* __restrict__ src, const int* __restrict__ dst,
                               const float* __restrict__ nf, const float* __restrict__ rs_out,
                               float* h_agg, int E){
  int gid = blockIdx.x*256 + threadIdx.x;
  int e = gid >> 7, f = gid & 127;
  if (e < E && f < IN_DIM){
    int s = src[e], d = dst[e];
    atomicAdd(&h_agg[d*IN_DIM + f], nf[s*IN_DIM + f] * rs_out[s]);
  }
}
// h = relu((h_agg * rs_in) @ W_gc + b_gc)    [N,74] -> [N,128]
__global__ __launch_bounds__(256) void k_gc_gemm(const float* __restrict__ h_agg,
        const float* __restrict__ rs_in, const float* __restrict__ W,
        const float* __restrict__ bias, float* __restrict__ h, int N){
  __shared__ float Wl[IN_DIM*HID];
  __shared__ float rows[8][IN_DIM];
  int base = blockIdx.x * 8;
  for (int idx = threadIdx.x; idx < IN_DIM*HID; idx += 256) Wl[idx] = W[idx];
  for (int idx = threadIdx.x; idx < 8*IN_DIM; idx += 256){
    int r = idx / IN_DIM, k = idx - r*IN_DIM;
    rows[r][k] = h_agg[(size_t)(base+r)*IN_DIM + k] * rs_in[base+r];
  }
  __syncthreads();
  int c = threadIdx.x & 127, rh = threadIdx.x >> 7;
  float a0=0,a1=0,a2=0,a3=0;
  for (int k = 0; k < IN_DIM; ++k){
    float w = Wl[k*HID + c];
    a0 += rows[rh  ][k]*w; a1 += rows[rh+2][k]*w;
    a2 += rows[rh+4][k]*w; a3 += rows[rh+6][k]*w;
  }
  float bv = bias[c];
  h[(size_t)(base+rh  )*HID+c] = fmaxf(a0+bv,0.f);
  h[(size_t)(base+rh+2)*HID+c] = fmaxf(a1+bv,0.f);
  h[(size_t)(base+rh+4)*HID+c] = fmaxf(a2+bv,0.f);
  h[(size_t)(base+rh+6)*HID+c] = fmaxf(a3+bv,0.f);
}
// S[g] = sum of h rows in graph g (graph_ids sorted); cnt[g] = row count
__global__ void k_segsum(const float* __restrict__ h, const int* __restrict__ gid,
                         float* S, float* cnt, int N){
  __shared__ int bounds[2];
  int g = blockIdx.x;
  if (threadIdx.x < 2){
    int target = g + (int)threadIdx.x;
    int lo = 0, hi = N;
    while (lo < hi){ int mid = (lo+hi)>>1; if (gid[mid] < target) lo = mid+1; else hi = mid; }
    bounds[threadIdx.x] = lo;
  }
  __syncthreads();
  int lo = bounds[0], hi = bounds[1];
  int c = threadIdx.x;
  float s = 0.f;
  for (int i = lo; i < hi; ++i) s += h[(size_t)i*HID + c];
  S[(size_t)g*HID + c] = s;
  if (c == 0) cnt[g] = (float)(hi - lo);
}
// out[r,c] = act( A[r,:K] @ W[:,c] + bias[c]*(bscale?bscale[r]:1) ), block = C threads
__global__ void k_gemm_small(const float* __restrict__ A, int AS, const float* __restrict__ W,
                             const float* __restrict__ bias, const float* __restrict__ bscale,
                             float* __restrict__ out, int OS, int K, int act){
  __shared__ float arow[256];
  int r = blockIdx.x, c = threadIdx.x, C = blockDim.x;
  for (int k = c; k < K; k += C) arow[k] = A[(size_t)r*AS + k];
  __syncthreads();
  float s = 0.f;
  for (int k = 0; k < K; ++k) s += arow[k] * W[(size_t)k*C + c];
  s += bias[c] * (bscale ? bscale[r] : 1.f);
  if (act) s = fmaxf(s, 0.f);
  out[(size_t)r*OS + c] = s;
}

// ---------- protein branch ----------
__global__ void k_embed(const int* __restrict__ seq, const float* __restrict__ emb,
                        u16* __restrict__ pv, int total){
  int idx = blockIdx.x*256 + threadIdx.x;
  if (idx >= total) return;
  int l = idx % LSEQ;
  int rem = idx / LSEQ;
  int c = rem & (HID-1);
  int b = rem >> 7;
  int tok = seq[b*LSEQ + l];
  pv[idx] = f2bf(emb[tok*HID + c]);
}

template<int CIN, int COUT>
__global__ __launch_bounds__(256) void k_conv(const u16* __restrict__ in, const float* __restrict__ Kw,
                                              const float* __restrict__ bias, u16* __restrict__ out){
  const int LT = 128, RSd = 66;          // 66 dwords = 132 bf16 per LDS row
  __shared__ u32 tileW[CIN*RSd];
  u16* tile = (u16*)tileW;
  int b = blockIdx.y;
  int lbase = blockIdx.x * LT;
  const u16* inb = in + (size_t)b*CIN*LSEQ;
  for (int idx = threadIdx.x; idx < CIN*RSd*2; idx += 256){
    int ci = idx / (RSd*2);
    int j  = idx - ci*(RSd*2);
    u16 v = 0;
    if (j < LT+2){
      int g = lbase - 1 + j;                       // tile[j] = input at l = lbase-1+j
      if (g >= 0 && g < LSEQ) v = inb[(size_t)ci*LSEQ + g];
    }
    tile[idx] = v;
  }
  __syncthreads();
  int ll  = threadIdx.x & 31;
  int l0  = ll * 4;
  int cog = threadIdx.x >> 5;
  int l   = lbase + l0;
  for (int co = cog; co < COUT; co += 8){
    float a0=0,a1=0,a2=0,a3=0;
    const float* kp = Kw + (size_t)co*CIN*3;
    for (int ci = 0; ci < CIN; ++ci){
      const u32* t = tileW + ci*RSd + ll*2;
      u32 u0 = t[0], u1 = t[1], u2 = t[2];
      float w0 = kp[0], w1 = kp[1], w2 = kp[2]; kp += 3;
      float x0 = bf2f(u0 & 0xffffu), x1 = bf2f(u0 >> 16);
      float x2 = bf2f(u1 & 0xffffu), x3 = bf2f(u1 >> 16);
      float x4 = bf2f(u2 & 0xffffu), x5 = bf2f(u2 >> 16);
      a0 += w0*x0 + w1*x1 + w2*x2;
      a1 += w0*x1 + w1*x2 + w2*x3;
      a2 += w0*x2 + w1*x3 + w2*x4;
      a3 += w0*x3 + w1*x4 + w2*x5;
    }
    float bv = bias[co];
    u16* ob = out + ((size_t)b*COUT + co)*LSEQ;
    if (l+0 < LSEQ) ob[l+0] = f2bf(fmaxf(a0+bv, 0.f));
    if (l+1 < LSEQ) ob[l+1] = f2bf(fmaxf(a1+bv, 0.f));
    if (l+2 < LSEQ) ob[l+2] = f2bf(fmaxf(a2+bv, 0.f));
    if (l+3 < LSEQ) ob[l+3] = f2bf(fmaxf(a3+bv, 0.f));
  }
}

__global__ void k_maxpool(const u16* __restrict__ pv, float* __restrict__ z){
  int c = blockIdx.x, b = blockIdx.y;
  const u16* p = pv + ((size_t)b*HID + c)*LSEQ;
  int lane = threadIdx.x;
  float m = -3.0e38f;
  for (int l = lane; l < LSEQ; l += 64) m = fmaxf(m, bf2f(p[l]));
  for (int o = 32; o; o >>= 1) m = fmaxf(m, __shfl_xor(m, o));
  if (lane == 0) z[(size_t)b*(2*HID) + HID + c] = m;
}

__global__ void k_head(const float* __restrict__ z2, const float* __restrict__ Wf2,
                       const float* __restrict__ bf2v, float* __restrict__ out){
  int b = blockIdx.x, lane = threadIdx.x;
  float s = 0.f;
  for (int k = lane; k < 2*HID; k += 64) s += z2[(size_t)b*(2*HID) + k] * Wf2[k];
  for (int o = 32; o; o >>= 1) s += __shfl_xor(s, o);
  if (lane == 0) out[b] = 1.f / (1.f + __expf(-(s + bf2v[0])));
}

extern "C" void kernel_launch(void* const* d_in, const int* in_sizes, int n_in,
                              void* d_out, int out_size, void* d_ws, size_t ws_size,
                              hipStream_t stream){
  const float* nf   = (const float*)d_in[0];
  const float* W_gc = (const float*)d_in[1];
  const float* b_gc = (const float*)d_in[2];
  const float* W_ri = (const float*)d_in[3];
  const float* b_ri = (const float*)d_in[4];
  const float* W_ro = (const float*)d_in[5];
  const float* b_ro = (const float*)d_in[6];
  const float* Wc1  = (const float*)d_in[7];
  const float* bc1  = (const float*)d_in[8];
  const float* Wc2  = (const float*)d_in[9];
  const float* bc2  = (const float*)d_in[10];
  const float* emb  = (const float*)d_in[11];
  const float* K1 = (const float*)d_in[12]; const float* cb1 = (const float*)d_in[13];
  const float* K2 = (const float*)d_in[14]; const float* cb2 = (const float*)d_in[15];
  const float* K3 = (const float*)d_in[16]; const float* cb3 = (const float*)d_in[17];
  const float* K4 = (const float*)d_in[18]; const float* cb4 = (const float*)d_in[19];
  const float* Wf1 = (const float*)d_in[20]; const float* bf1 = (const float*)d_in[21];
  const float* Wf2 = (const float*)d_in[22]; const float* bf2v = (const float*)d_in[23];
  const int* esrc = (const int*)d_in[24];
  const int* edst = (const int*)d_in[25];
  const int* gids = (const int*)d_in[26];
  const int* seq  = (const int*)d_in[27];
  float* out = (float*)d_out;

  int N = in_sizes[26];
  int E = in_sizes[24];
  int B = out_size;            // output is [B,1]

  char* ws = (char*)d_ws;
  size_t off = 0;
  auto take = [&](size_t bytes)->char*{
    char* p = ws + off; off = (off + bytes + 255) & ~(size_t)255; return p;
  };
  float* rs_out = (float*)take((size_t)N*4);
  float* rs_in  = (float*)take((size_t)N*4);
  float* S    = (float*)take((size_t)B*HID*4);
  float* cnt  = (float*)take((size_t)B*4);
  float* T    = (float*)take((size_t)B*HID*4);
  float* hg   = (float*)take((size_t)B*HID*4);
  float* cv1  = (float*)take((size_t)B*HID*4);
  float* z    = (float*)take((size_t)B*2*HID*4);
  float* z2   = (float*)take((size_t)B*2*HID*4);
  size_t bigoff = off;
  size_t PV = (size_t)B*HID*LSEQ*2;            // bf16 ping-pong buffers
  u16* pvA = (u16*)(ws + bigoff);
  u16* pvB = (u16*)(ws + bigoff + PV);
  // graph scratch overlaps pvA/pvB region — graph branch completes before embed writes
  float* h_agg = (float*)(ws + bigoff);
  float* h     = (float*)(ws + bigoff + (size_t)N*IN_DIM*4);

  // ---- graph branch ----
  k_deg_init <<<(N+255)/256, 256, 0, stream>>>(rs_out, rs_in, N);
  k_deg_edge <<<(E+255)/256, 256, 0, stream>>>(esrc, edst, rs_out, rs_in, E);
  k_deg_rsqrt<<<(N+255)/256, 256, 0, stream>>>(rs_out, rs_in, N);
  int tot74 = N * IN_DIM;
  k_init_hagg<<<(tot74+255)/256, 256, 0, stream>>>(nf, rs_out, h_agg, tot74);
  long long escat = (long long)E * 128;
  k_edge_scatter<<<(unsigned)((escat+255)/256), 256, 0, stream>>>(esrc, edst, nf, rs_out, h_agg, E);
  k_gc_gemm<<<N/8, 256, 0, stream>>>(h_agg, rs_in, W_gc, b_gc, h, N);
  k_segsum <<<B, HID, 0, stream>>>(h, gids, S, cnt, N);
  k_gemm_small<<<B, HID, 0, stream>>>(S,   HID, W_ri, b_ri, cnt,     T,   HID,   HID, 0);
  k_gemm_small<<<B, HID, 0, stream>>>(T,   HID, W_ro, b_ro, cnt,     hg,  HID,   HID, 1);
  k_gemm_small<<<B, HID, 0, stream>>>(hg,  HID, Wc1,  bc1,  nullptr, cv1, HID,   HID, 1);
  k_gemm_small<<<B, HID, 0, stream>>>(cv1, HID, Wc2,  bc2,  nullptr, z,   2*HID, HID, 1);

  // ---- protein branch ----
  int total = B * HID * LSEQ;
  k_embed<<<(total+255)/256, 256, 0, stream>>>(seq, emb, pvA, total);
  dim3 cgrid((LSEQ + 127)/128, B);
  k_conv<128, 96><<<cgrid, 256, 0, stream>>>(pvA, K1, cb1, pvB);
  k_conv< 96,128><<<cgrid, 256, 0, stream>>>(pvB, K2, cb2, pvA);
  k_conv<128, 74><<<cgrid, 256, 0, stream>>>(pvA, K3, cb3, pvB);
  k_conv< 74,128><<<cgrid, 256, 0, stream>>>(pvB, K4, cb4, pvA);
  k_maxpool<<<dim3(HID, B), 64, 0, stream>>>(pvA, z);

  // ---- head ----
  k_gemm_small<<<B, 2*HID, 0, stream>>>(z, 2*HID, Wf1, bf1, nullptr, z2, 2*HID, 2*HID, 1);
  k_head<<<B, 64, 0, stream>>>(z2, Wf2, bf2v, out);
}

// Round 2
// 1123.966 us; speedup vs baseline: 3.1842x; 3.1842x over previous
//
#include <hip/hip_runtime.h>
#include <math.h>

#define IN_DIM 74
#define HID 128
#define LSEQ 1000

typedef unsigned int u32;
typedef unsigned short u16;

typedef __attribute__((ext_vector_type(8))) short bf16x8;
typedef __attribute__((ext_vector_type(4))) float f32x4;

__device__ __forceinline__ float bf2f(u32 lo16){ return __uint_as_float(lo16 << 16); }
__device__ __forceinline__ u16 f2bf(float f){
  u32 u = __float_as_uint(f);
  u32 r = (u + 0x7fffu + ((u >> 16) & 1u)) >> 16;   // round-nearest-even
  return (u16)r;
}

// ---------- graph branch ----------
__global__ void k_deg_init(float* rs_out, float* rs_in, int N){
  int i = blockIdx.x*256 + threadIdx.x;
  if (i < N){ rs_out[i] = 1.f; rs_in[i] = 1.f; }   // self-loop counts as 1
}
__global__ void k_deg_edge(const int* __restrict__ src, const int* __restrict__ dst,
                           float* rs_out, float* rs_in, int E){
  int e = blockIdx.x*256 + threadIdx.x;
  if (e < E){ atomicAdd(&rs_out[src[e]], 1.f); atomicAdd(&rs_in[dst[e]], 1.f); }
}
__global__ void k_deg_rsqrt(float* rs_out, float* rs_in, int N){
  int i = blockIdx.x*256 + threadIdx.x;
  if (i < N){ rs_out[i] = rsqrtf(rs_out[i]); rs_in[i] = rsqrtf(rs_in[i]); }
}
__global__ void k_init_hagg(const float* __restrict__ nf, const float* __restrict__ rs_out,
                            float* h_agg, int total){
  int idx = blockIdx.x*256 + threadIdx.x;
  if (idx < total) h_agg[idx] = nf[idx] * rs_out[idx / IN_DIM];
}
__global__ void k_edge_scatter(const int* __restrict__ src, const int* __restrict__ dst,
                               const float* __restrict__ nf, const float* __restrict__ rs_out,
                               float* h_agg, int E){
  int gid = blockIdx.x*256 + threadIdx.x;
  int e = gid >> 7, f = gid & 127;
  if (e < E && f < IN_DIM){
    int s = src[e], d = dst[e];
    atomicAdd(&h_agg[d*IN_DIM + f], nf[s*IN_DIM + f] * rs_out[s]);
  }
}
__global__ __launch_bounds__(256) void k_gc_gemm(const float* __restrict__ h_agg,
        const float* __restrict__ rs_in, const float* __restrict__ W,
        const float* __restrict__ bias, float* __restrict__ h, int N){
  __shared__ float Wl[IN_DIM*HID];
  __shared__ float rows[8][IN_DIM];
  int base = blockIdx.x * 8;
  for (int idx = threadIdx.x; idx < IN_DIM*HID; idx += 256) Wl[idx] = W[idx];
  for (int idx = threadIdx.x; idx < 8*IN_DIM; idx += 256){
    int r = idx / IN_DIM, k = idx - r*IN_DIM;
    rows[r][k] = h_agg[(size_t)(base+r)*IN_DIM + k] * rs_in[base+r];
  }
  __syncthreads();
  int c = threadIdx.x & 127, rh = threadIdx.x >> 7;
  float a0=0,a1=0,a2=0,a3=0;
  for (int k = 0; k < IN_DIM; ++k){
    float w = Wl[k*HID + c];
    a0 += rows[rh  ][k]*w; a1 += rows[rh+2][k]*w;
    a2 += rows[rh+4][k]*w; a3 += rows[rh+6][k]*w;
  }
  float bv = bias[c];
  h[(size_t)(base+rh  )*HID+c] = fmaxf(a0+bv,0.f);
  h[(size_t)(base+rh+2)*HID+c] = fmaxf(a1+bv,0.f);
  h[(size_t)(base+rh+4)*HID+c] = fmaxf(a2+bv,0.f);
  h[(size_t)(base+rh+6)*HID+c] = fmaxf(a3+bv,0.f);
}
__global__ void k_segsum(const float* __restrict__ h, const int* __restrict__ gid,
                         float* S, float* cnt, int N){
  __shared__ int bounds[2];
  int g = blockIdx.x;
  if (threadIdx.x < 2){
    int target = g + (int)threadIdx.x;
    int lo = 0, hi = N;
    while (lo < hi){ int mid = (lo+hi)>>1; if (gid[mid] < target) lo = mid+1; else hi = mid; }
    bounds[threadIdx.x] = lo;
  }
  __syncthreads();
  int lo = bounds[0], hi = bounds[1];
  int c = threadIdx.x;
  float s = 0.f;
  for (int i = lo; i < hi; ++i) s += h[(size_t)i*HID + c];
  S[(size_t)g*HID + c] = s;
  if (c == 0) cnt[g] = (float)(hi - lo);
}
__global__ void k_gemm_small(const float* __restrict__ A, int AS, const float* __restrict__ W,
                             const float* __restrict__ bias, const float* __restrict__ bscale,
                             float* __restrict__ out, int OS, int K, int act){
  __shared__ float arow[256];
  int r = blockIdx.x, c = threadIdx.x, C = blockDim.x;
  for (int k = c; k < K; k += C) arow[k] = A[(size_t)r*AS + k];
  __syncthreads();
  float s = 0.f;
  for (int k = 0; k < K; ++k) s += arow[k] * W[(size_t)k*C + c];
  s += bias[c] * (bscale ? bscale[r] : 1.f);
  if (act) s = fmaxf(s, 0.f);
  out[(size_t)r*OS + c] = s;
}

// ---------- protein branch (channel-last, MFMA) ----------

// prepack weights: Apack[co][k], k = t*CPAD + ci (bf16, zero-padded); bpad[co]
__global__ void k_prepack(const float* __restrict__ Kw, const float* __restrict__ bsrc,
                          u16* __restrict__ Apack, float* __restrict__ bpad,
                          int CIN, int CPAD, int COUT, int OPAD){
  int K = 3*CPAD;
  int idx = blockIdx.x*256 + threadIdx.x;
  if (idx < OPAD*K){
    int co = idx / K, k = idx - co*K;
    int t = k / CPAD, ci = k - t*CPAD;
    float v = (co < COUT && ci < CIN) ? Kw[((size_t)co*CIN + ci)*3 + t] : 0.f;
    Apack[idx] = f2bf(v);
  }
  if (idx < OPAD) bpad[idx] = (idx < COUT) ? bsrc[idx] : 0.f;
}

// embed -> X[b][l][128] bf16 (channel-last)
__global__ void k_embed2(const int* __restrict__ seq, const float* __restrict__ emb,
                         u16* __restrict__ X){
  int g = blockIdx.x*256 + threadIdx.x;
  int row = g >> 4;                 // b*1000 + l
  int c0 = (g & 15) * 8;
  if (row >= 512*LSEQ) return;
  int tok = seq[row];
  const float4* e = (const float4*)(emb + (size_t)tok*HID + c0);
  float4 v0 = e[0], v1 = e[1];
  u16 o[8] = { f2bf(v0.x), f2bf(v0.y), f2bf(v0.z), f2bf(v0.w),
               f2bf(v1.x), f2bf(v1.y), f2bf(v1.z), f2bf(v1.w) };
  *(uint4*)(X + (size_t)row*HID + c0) = *(uint4*)o;
}

// conv1d(k=3,pad=1) as MFMA GEMM over channel-last tiles.
// Xin [512][1000][CPAD] bf16, Apack [OPAD][3*CPAD] bf16, Xout [512][1000][OPAD] bf16
template<int CPAD, int OPAD>
__global__ __launch_bounds__(256) void k_conv_mfma(
    const u16* __restrict__ Xin, const u16* __restrict__ Apack,
    const float* __restrict__ bpad, u16* __restrict__ Xout){
  constexpr int K = 3*CPAD;
  constexpr int STRIDE = CPAD*2;          // LDS row bytes
  constexpr int MF = OPAD/16;
  constexpr int ROWS = 130;               // l0-1 .. l0+128
  __shared__ __align__(16) char smem[ROWS*STRIDE];

  const int tid = threadIdx.x;
  const int b = blockIdx.y;
  const int l0 = blockIdx.x * 128;

  // stage X[l0-1 .. l0+128][:] -> LDS with per-row XOR swizzle (T2)
  const char* xbase = (const char*)(Xin + (size_t)b*LSEQ*CPAD) + (long)(l0-1)*STRIDE;
  for (int pos = tid*16; pos < ROWS*STRIDE; pos += 256*16){
    int row = pos / STRIDE;
    int cb  = pos - row*STRIDE;
    int l = l0 - 1 + row;
    uint4 v = make_uint4(0u,0u,0u,0u);
    if (l >= 0 && l < LSEQ) v = *(const uint4*)(xbase + pos);
    int swz = (CPAD == 128) ? ((row & 7) << 4) : ((row & 3) << 4);
    *(uint4*)(smem + row*STRIDE + (cb ^ swz)) = v;
  }
  __syncthreads();

  const int lane = tid & 63;
  const int wid  = tid >> 6;
  const int lm   = lane & 15;
  const int cg   = lane >> 4;
  const int wrow = wid*32 + lm;           // wave's l-offset within tile

  f32x4 acc[MF][2];
  #pragma unroll
  for (int mi = 0; mi < MF; ++mi){
    acc[mi][0] = (f32x4){0.f,0.f,0.f,0.f};
    acc[mi][1] = (f32x4){0.f,0.f,0.f,0.f};
  }

  #pragma unroll
  for (int ks = 0; ks < K/32; ++ks){
    const int t   = (ks*32) / CPAD;                 // tap (section aligned to 32)
    const int cb0 = ((ks*32) % CPAD)*2 + cg*16;     // byte offset of lane's 8 ci's
    int r0 = wrow + t;
    int sw0 = (CPAD == 128) ? ((r0 & 7) << 4) : ((r0 & 3) << 4);
    bf16x8 B0 = *(const bf16x8*)(smem + r0*STRIDE + (cb0 ^ sw0));
    int r1 = r0 + 16;
    int sw1 = (CPAD == 128) ? ((r1 & 7) << 4) : ((r1 & 3) << 4);
    bf16x8 B1 = *(const bf16x8*)(smem + r1*STRIDE + (cb0 ^ sw1));
    #pragma unroll
    for (int mi = 0; mi < MF; ++mi){
      bf16x8 Af = *(const bf16x8*)(Apack + (size_t)(mi*16 + lm)*K + ks*32 + cg*8);
      acc[mi][0] = __builtin_amdgcn_mfma_f32_16x16x32_bf16(Af, B0, acc[mi][0], 0, 0, 0);
      acc[mi][1] = __builtin_amdgcn_mfma_f32_16x16x32_bf16(Af, B1, acc[mi][1], 0, 0, 0);
    }
  }

  // epilogue: bias + relu + bf16 pack; C/D layout col=lane&15 (l), row=cg*4+r (co)
  #pragma unroll
  for (int mi = 0; mi < MF; ++mi){
    int co0 = mi*16 + cg*4;
    float b0 = bpad[co0], b1 = bpad[co0+1], b2 = bpad[co0+2], b3 = bpad[co0+3];
    #pragma unroll
    for (int ni = 0; ni < 2; ++ni){
      int l = l0 + wid*32 + ni*16 + lm;
      if (l < LSEQ){
        f32x4 a = acc[mi][ni];
        u32 lo = (u32)f2bf(fmaxf(a[0]+b0, 0.f)) | ((u32)f2bf(fmaxf(a[1]+b1, 0.f)) << 16);
        u32 hi = (u32)f2bf(fmaxf(a[2]+b2, 0.f)) | ((u32)f2bf(fmaxf(a[3]+b3, 0.f)) << 16);
        uint2 st; st.x = lo; st.y = hi;
        *(uint2*)(Xout + ((size_t)b*LSEQ + l)*OPAD + co0) = st;
      }
    }
  }
}

// global max over l: X[b][l][128] -> z[b][128+c]
__global__ __launch_bounds__(256) void k_maxpool2(const u16* __restrict__ X, float* __restrict__ z){
  __shared__ float red[256][8];
  int b = blockIdx.x;
  int coct = threadIdx.x & 15, part = threadIdx.x >> 4;
  float m[8];
  #pragma unroll
  for (int j = 0; j < 8; ++j) m[j] = 0.f;   // post-ReLU values are >= 0
  const u16* Xb = X + (size_t)b*LSEQ*HID + coct*8;
  for (int l = part; l < LSEQ; l += 16){
    uint4 v = *(const uint4*)(Xb + (size_t)l*HID);
    u32 w[4] = {v.x, v.y, v.z, v.w};
    #pragma unroll
    for (int j = 0; j < 4; ++j){
      m[2*j]   = fmaxf(m[2*j],   bf2f(w[j] & 0xffffu));
      m[2*j+1] = fmaxf(m[2*j+1], bf2f(w[j] >> 16));
    }
  }
  #pragma unroll
  for (int j = 0; j < 8; ++j) red[threadIdx.x][j] = m[j];
  __syncthreads();
  if (threadIdx.x < 16){
    int c = threadIdx.x;
    float mm[8];
    #pragma unroll
    for (int j = 0; j < 8; ++j) mm[j] = red[c][j];
    for (int p = 1; p < 16; ++p)
      #pragma unroll
      for (int j = 0; j < 8; ++j) mm[j] = fmaxf(mm[j], red[p*16 + c][j]);
    for (int j = 0; j < 8; ++j) z[(size_t)b*(2*HID) + HID + c*8 + j] = mm[j];
  }
}

__global__ void k_head(const float* __restrict__ z2, const float* __restrict__ Wf2,
                       const float* __restrict__ bf2v, float* __restrict__ out){
  int b = blockIdx.x, lane = threadIdx.x;
  float s = 0.f;
  for (int k = lane; k < 2*HID; k += 64) s += z2[(size_t)b*(2*HID) + k] * Wf2[k];
  for (int o = 32; o; o >>= 1) s += __shfl_xor(s, o);
  if (lane == 0) out[b] = 1.f / (1.f + __expf(-(s + bf2v[0])));
}

extern "C" void kernel_launch(void* const* d_in, const int* in_sizes, int n_in,
                              void* d_out, int out_size, void* d_ws, size_t ws_size,
                              hipStream_t stream){
  const float* nf   = (const float*)d_in[0];
  const float* W_gc = (const float*)d_in[1];
  const float* b_gc = (const float*)d_in[2];
  const float* W_ri = (const float*)d_in[3];
  const float* b_ri = (const float*)d_in[4];
  const float* W_ro = (const float*)d_in[5];
  const float* b_ro = (const float*)d_in[6];
  const float* Wc1  = (const float*)d_in[7];
  const float* bc1  = (const float*)d_in[8];
  const float* Wc2  = (const float*)d_in[9];
  const float* bc2  = (const float*)d_in[10];
  const float* emb  = (const float*)d_in[11];
  const float* K1 = (const float*)d_in[12]; const float* cb1 = (const float*)d_in[13];
  const float* K2 = (const float*)d_in[14]; const float* cb2 = (const float*)d_in[15];
  const float* K3 = (const float*)d_in[16]; const float* cb3 = (const float*)d_in[17];
  const float* K4 = (const float*)d_in[18]; const float* cb4 = (const float*)d_in[19];
  const float* Wf1 = (const float*)d_in[20]; const float* bf1 = (const float*)d_in[21];
  const float* Wf2 = (const float*)d_in[22]; const float* bf2v = (const float*)d_in[23];
  const int* esrc = (const int*)d_in[24];
  const int* edst = (const int*)d_in[25];
  const int* gids = (const int*)d_in[26];
  const int* seq  = (const int*)d_in[27];
  float* out = (float*)d_out;

  int N = in_sizes[26];
  int E = in_sizes[24];
  int B = out_size;

  char* ws = (char*)d_ws;
  size_t off = 0;
  auto take = [&](size_t bytes)->char*{
    char* p = ws + off; off = (off + bytes + 255) & ~(size_t)255; return p;
  };
  float* rs_out = (float*)take((size_t)N*4);
  float* rs_in  = (float*)take((size_t)N*4);
  float* S    = (float*)take((size_t)B*HID*4);
  float* cnt  = (float*)take((size_t)B*4);
  float* T    = (float*)take((size_t)B*HID*4);
  float* hg   = (float*)take((size_t)B*HID*4);
  float* cv1  = (float*)take((size_t)B*HID*4);
  float* z    = (float*)take((size_t)B*2*HID*4);
  float* z2   = (float*)take((size_t)B*2*HID*4);
  u16* Ap1 = (u16*)take((size_t)96*384*2);  float* bp1 = (float*)take(96*4);
  u16* Ap2 = (u16*)take((size_t)128*288*2); float* bp2 = (float*)take(128*4);
  u16* Ap3 = (u16*)take((size_t)96*384*2);  float* bp3 = (float*)take(96*4);
  u16* Ap4 = (u16*)take((size_t)128*288*2); float* bp4 = (float*)take(128*4);
  size_t bigoff = off;
  u16* XA = (u16*)take((size_t)B*LSEQ*128*2);   // 131 MB, 128-wide activations
  u16* XB = (u16*)take((size_t)B*LSEQ*96*2);    // 98 MB, 96-wide activations
  // graph scratch overlaps XA (graph branch completes before embed writes)
  float* h_agg = (float*)(ws + bigoff);
  float* h     = (float*)(ws + bigoff + (size_t)N*IN_DIM*4);

  // ---- graph branch ----
  k_deg_init <<<(N+255)/256, 256, 0, stream>>>(rs_out, rs_in, N);
  k_deg_edge <<<(E+255)/256, 256, 0, stream>>>(esrc, edst, rs_out, rs_in, E);
  k_deg_rsqrt<<<(N+255)/256, 256, 0, stream>>>(rs_out, rs_in, N);
  int tot74 = N * IN_DIM;
  k_init_hagg<<<(tot74+255)/256, 256, 0, stream>>>(nf, rs_out, h_agg, tot74);
  long long escat = (long long)E * 128;
  k_edge_scatter<<<(unsigned)((escat+255)/256), 256, 0, stream>>>(esrc, edst, nf, rs_out, h_agg, E);
  k_gc_gemm<<<N/8, 256, 0, stream>>>(h_agg, rs_in, W_gc, b_gc, h, N);
  k_segsum <<<B, HID, 0, stream>>>(h, gids, S, cnt, N);
  k_gemm_small<<<B, HID, 0, stream>>>(S,   HID, W_ri, b_ri, cnt,     T,   HID,   HID, 0);
  k_gemm_small<<<B, HID, 0, stream>>>(T,   HID, W_ro, b_ro, cnt,     hg,  HID,   HID, 1);
  k_gemm_small<<<B, HID, 0, stream>>>(hg,  HID, Wc1,  bc1,  nullptr, cv1, HID,   HID, 1);
  k_gemm_small<<<B, HID, 0, stream>>>(cv1, HID, Wc2,  bc2,  nullptr, z,   2*HID, HID, 1);

  // ---- protein branch ----
  k_prepack<<<(96*384 +255)/256, 256, 0, stream>>>(K1, cb1, Ap1, bp1, 128, 128,  96,  96);
  k_prepack<<<(128*288+255)/256, 256, 0, stream>>>(K2, cb2, Ap2, bp2,  96,  96, 128, 128);
  k_prepack<<<(96*384 +255)/256, 256, 0, stream>>>(K3, cb3, Ap3, bp3, 128, 128,  74,  96);
  k_prepack<<<(128*288+255)/256, 256, 0, stream>>>(K4, cb4, Ap4, bp4,  74,  96, 128, 128);
  k_embed2<<<(512*LSEQ*16 + 255)/256, 256, 0, stream>>>(seq, emb, XA);
  dim3 cgrid(8, B);
  k_conv_mfma<128, 96><<<cgrid, 256, 0, stream>>>(XA, Ap1, bp1, XB);
  k_conv_mfma< 96,128><<<cgrid, 256, 0, stream>>>(XB, Ap2, bp2, XA);
  k_conv_mfma<128, 96><<<cgrid, 256, 0, stream>>>(XA, Ap3, bp3, XB);
  k_conv_mfma< 96,128><<<cgrid, 256, 0, stream>>>(XB, Ap4, bp4, XA);
  k_maxpool2<<<B, 256, 0, stream>>>(XA, z);

  // ---- head ----
  k_gemm_small<<<B, 2*HID, 0, stream>>>(z, 2*HID, Wf1, bf1, nullptr, z2, 2*HID, 2*HID, 1);
  k_head<<<B, 64, 0, stream>>>(z2, Wf2, bf2v, out);
}

// Round 3
// 834.364 us; speedup vs baseline: 4.2894x; 1.3471x over previous
//
#include <hip/hip_runtime.h>
#include <math.h>

#define IN_DIM 74
#define HID 128
#define LSEQ 1000

typedef unsigned int u32;
typedef unsigned short u16;

typedef __attribute__((ext_vector_type(8))) short bf16x8;
typedef __attribute__((ext_vector_type(4))) float f32x4;

__device__ __forceinline__ float bf2f(u32 lo16){ return __uint_as_float(lo16 << 16); }
__device__ __forceinline__ u16 f2bf(float f){
  u32 u = __float_as_uint(f);
  u32 r = (u + 0x7fffu + ((u >> 16) & 1u)) >> 16;   // round-nearest-even
  return (u16)r;
}

// ---------- graph branch ----------
__global__ void k_deg_init(float* rs_out, float* rs_in, int N){
  int i = blockIdx.x*256 + threadIdx.x;
  if (i < N){ rs_out[i] = 1.f; rs_in[i] = 1.f; }   // self-loop counts as 1
}
__global__ void k_deg_edge(const int* __restrict__ src, const int* __restrict__ dst,
                           float* rs_out, float* rs_in, int E){
  int e = blockIdx.x*256 + threadIdx.x;
  if (e < E){ atomicAdd(&rs_out[src[e]], 1.f); atomicAdd(&rs_in[dst[e]], 1.f); }
}
__global__ void k_deg_rsqrt(float* rs_out, float* rs_in, int N){
  int i = blockIdx.x*256 + threadIdx.x;
  if (i < N){ rs_out[i] = rsqrtf(rs_out[i]); rs_in[i] = rsqrtf(rs_in[i]); }
}
__global__ void k_init_hagg(const float* __restrict__ nf, const float* __restrict__ rs_out,
                            float* h_agg, int total){
  int idx = blockIdx.x*256 + threadIdx.x;
  if (idx < total) h_agg[idx] = nf[idx] * rs_out[idx / IN_DIM];
}
__global__ void k_edge_scatter(const int* __restrict__ src, const int* __restrict__ dst,
                               const float* __restrict__ nf, const float* __restrict__ rs_out,
                               float* h_agg, int E){
  int gid = blockIdx.x*256 + threadIdx.x;
  int e = gid >> 7, f = gid & 127;
  if (e < E && f < IN_DIM){
    int s = src[e], d = dst[e];
    atomicAdd(&h_agg[d*IN_DIM + f], nf[s*IN_DIM + f] * rs_out[s]);
  }
}
__global__ __launch_bounds__(256) void k_gc_gemm(const float* __restrict__ h_agg,
        const float* __restrict__ rs_in, const float* __restrict__ W,
        const float* __restrict__ bias, float* __restrict__ h, int N){
  __shared__ float Wl[IN_DIM*HID];
  __shared__ float rows[8][IN_DIM];
  int base = blockIdx.x * 8;
  for (int idx = threadIdx.x; idx < IN_DIM*HID; idx += 256) Wl[idx] = W[idx];
  for (int idx = threadIdx.x; idx < 8*IN_DIM; idx += 256){
    int r = idx / IN_DIM, k = idx - r*IN_DIM;
    rows[r][k] = h_agg[(size_t)(base+r)*IN_DIM + k] * rs_in[base+r];
  }
  __syncthreads();
  int c = threadIdx.x & 127, rh = threadIdx.x >> 7;
  float a0=0,a1=0,a2=0,a3=0;
  for (int k = 0; k < IN_DIM; ++k){
    float w = Wl[k*HID + c];
    a0 += rows[rh  ][k]*w; a1 += rows[rh+2][k]*w;
    a2 += rows[rh+4][k]*w; a3 += rows[rh+6][k]*w;
  }
  float bv = bias[c];
  h[(size_t)(base+rh  )*HID+c] = fmaxf(a0+bv,0.f);
  h[(size_t)(base+rh+2)*HID+c] = fmaxf(a1+bv,0.f);
  h[(size_t)(base+rh+4)*HID+c] = fmaxf(a2+bv,0.f);
  h[(size_t)(base+rh+6)*HID+c] = fmaxf(a3+bv,0.f);
}
__global__ void k_segsum(const float* __restrict__ h, const int* __restrict__ gid,
                         float* S, float* cnt, int N){
  __shared__ int bounds[2];
  int g = blockIdx.x;
  if (threadIdx.x < 2){
    int target = g + (int)threadIdx.x;
    int lo = 0, hi = N;
    while (lo < hi){ int mid = (lo+hi)>>1; if (gid[mid] < target) lo = mid+1; else hi = mid; }
    bounds[threadIdx.x] = lo;
  }
  __syncthreads();
  int lo = bounds[0], hi = bounds[1];
  int c = threadIdx.x;
  float s = 0.f;
  for (int i = lo; i < hi; ++i) s += h[(size_t)i*HID + c];
  S[(size_t)g*HID + c] = s;
  if (c == 0) cnt[g] = (float)(hi - lo);
}
__global__ void k_gemm_small(const float* __restrict__ A, int AS, const float* __restrict__ W,
                             const float* __restrict__ bias, const float* __restrict__ bscale,
                             float* __restrict__ out, int OS, int K, int act){
  __shared__ float arow[256];
  int r = blockIdx.x, c = threadIdx.x, C = blockDim.x;
  for (int k = c; k < K; k += C) arow[k] = A[(size_t)r*AS + k];
  __syncthreads();
  float s = 0.f;
  for (int k = 0; k < K; ++k) s += arow[k] * W[(size_t)k*C + c];
  s += bias[c] * (bscale ? bscale[r] : 1.f);
  if (act) s = fmaxf(s, 0.f);
  out[(size_t)r*OS + c] = s;
}

// ---------- protein branch (channel-last, MFMA, per-batch persistent) ----------

__global__ void k_zero(u32* p, int n){ int i = blockIdx.x*64 + threadIdx.x; if (i < n) p[i] = 0; }

// prepack weights: Apack[co][k], k = t*CPAD + ci (bf16, zero-padded); bpad[co]
__global__ void k_prepack(const float* __restrict__ Kw, const float* __restrict__ bsrc,
                          u16* __restrict__ Apack, float* __restrict__ bpad,
                          int CIN, int CPAD, int COUT, int OPAD){
  int K = 3*CPAD;
  int idx = blockIdx.x*256 + threadIdx.x;
  if (idx < OPAD*K){
    int co = idx / K, k = idx - co*K;
    int t = k / CPAD, ci = k - t*CPAD;
    float v = (co < COUT && ci < CIN) ? Kw[((size_t)co*CIN + ci)*3 + t] : 0.f;
    Apack[idx] = f2bf(v);
  }
  if (idx < OPAD) bpad[idx] = (idx < COUT) ? bsrc[idx] : 0.f;
}

// embed -> X[b][l][128] bf16 (channel-last)
__global__ void k_embed2(const int* __restrict__ seq, const float* __restrict__ emb,
                         u16* __restrict__ X){
  int g = blockIdx.x*256 + threadIdx.x;
  int row = g >> 4;                 // b*1000 + l
  int c0 = (g & 15) * 8;
  if (row >= 512*LSEQ) return;
  int tok = seq[row];
  const float4* e = (const float4*)(emb + (size_t)tok*HID + c0);
  float4 v0 = e[0], v1 = e[1];
  u16 o[8] = { f2bf(v0.x), f2bf(v0.y), f2bf(v0.z), f2bf(v0.w),
               f2bf(v1.x), f2bf(v1.y), f2bf(v1.z), f2bf(v1.w) };
  *(uint4*)(X + (size_t)row*HID + c0) = *(uint4*)o;
}

// conv1d(k=3,pad=1) as MFMA GEMM; one block per batch, weights in registers,
// X double-buffered through LDS in 128-l chunks via global_load_lds.
// Wave grid: wid>>1 = co-half, wid&1 = l-half(64 l). CPAD=128 rows XOR-swizzled
// (inverse-swizzled global source, linear LDS dest, swizzled read — rule #21).
template<int CPAD, int OPAD>
__global__ __launch_bounds__(256, 2) void k_conv_batch(
    const u16* __restrict__ Xin, const u16* __restrict__ Apack,
    const float* __restrict__ bpad, u16* __restrict__ Xout,
    const u16* __restrict__ zbuf){
  constexpr int K  = 3*CPAD;
  constexpr int KS = K/32;                // k-steps of 32
  constexpr int MFH = OPAD/32;            // co 16-frags per wave (half of OPAD/16)
  constexpr int RB = CPAD*2;              // LDS/global row bytes
  constexpr int BUF = 130*RB;             // bytes per LDS buffer
  constexpr int SLOTS = BUF/16;
  constexpr int TPC = CPAD/32;            // ksteps per tap
  __shared__ __align__(16) char smem[2*BUF];

  const int tid  = threadIdx.x;
  const int lane = tid & 63;
  const int wid  = tid >> 6;
  const int lm   = lane & 15;
  const int cg   = lane >> 4;
  const int wr   = wid >> 1;
  const int wl   = wid & 1;
  const int co0  = wr * (OPAD/2);
  const int b    = blockIdx.x;
  const char* xb = (const char*)(Xin + (size_t)b * LSEQ * CPAD);

  // ---- preload A panel (this wave's co-half, all K) into registers ----
  bf16x8 Areg[KS][MFH];
  #pragma unroll
  for (int ks = 0; ks < KS; ++ks)
    #pragma unroll
    for (int m = 0; m < MFH; ++m)
      Areg[ks][m] = *(const bf16x8*)(Apack + (size_t)(co0 + m*16 + lm)*K + ks*32 + cg*8);

  float4 bb[MFH];
  #pragma unroll
  for (int m = 0; m < MFH; ++m)
    bb[m] = *(const float4*)(bpad + co0 + m*16 + cg*4);

  // ---- stage chunk t into buffer pbuf (async DMA, vmcnt-counted) ----
  auto stage = [&](int t, int pbuf){
    const int l0 = t*128;
    char* base = smem + pbuf*BUF;
    #pragma unroll
    for (int it = 0; it*256 < SLOTS; ++it){
      int pos = it*256 + tid;
      if (pos < SLOTS){
        int row, colg;
        if constexpr (CPAD == 128){ row = pos >> 4; colg = (pos & 15) ^ (row & 7); }
        else                      { row = pos / 12; colg = pos - row*12; }
        int l = l0 - 1 + row;
        const char* g = (l >= 0 && l < LSEQ) ? (xb + (size_t)l*RB + colg*16)
                                             : (const char*)zbuf;
        __builtin_amdgcn_global_load_lds(
            (const __attribute__((address_space(1))) unsigned*)g,
            (__attribute__((address_space(3))) unsigned*)(base + it*4096 + wid*1024),
            16, 0, 0);
      }
    }
  };

  // ---- compute chunk t from buffer pbuf ----
  auto compute = [&](int t, int pbuf){
    const char* base = smem + pbuf*BUF;
    f32x4 acc[MFH][4];
    #pragma unroll
    for (int m = 0; m < MFH; ++m)
      #pragma unroll
      for (int n = 0; n < 4; ++n)
        acc[m][n] = (f32x4){0.f,0.f,0.f,0.f};

    #pragma unroll
    for (int ks = 0; ks < KS; ++ks){
      const int tap = ks / TPC;
      const int c16 = (ks % TPC)*4 + cg;
      bf16x8 Bf[4];
      #pragma unroll
      for (int n = 0; n < 4; ++n){
        int row = wl*64 + n*16 + lm + tap;
        int col = (CPAD == 128) ? (c16 ^ (row & 7)) : c16;
        Bf[n] = *(const bf16x8*)(base + row*RB + col*16);
      }
      #pragma unroll
      for (int m = 0; m < MFH; ++m)
        #pragma unroll
        for (int n = 0; n < 4; ++n)
          acc[m][n] = __builtin_amdgcn_mfma_f32_16x16x32_bf16(Areg[ks][m], Bf[n], acc[m][n], 0, 0, 0);
    }

    const int l0 = t*128;
    #pragma unroll
    for (int m = 0; m < MFH; ++m){
      int co = co0 + m*16 + cg*4;
      #pragma unroll
      for (int n = 0; n < 4; ++n){
        int l = l0 + wl*64 + n*16 + lm;
        if (l < LSEQ){
          f32x4 a = acc[m][n];
          u32 lo = (u32)f2bf(fmaxf(a[0]+bb[m].x, 0.f)) | ((u32)f2bf(fmaxf(a[1]+bb[m].y, 0.f)) << 16);
          u32 hi = (u32)f2bf(fmaxf(a[2]+bb[m].z, 0.f)) | ((u32)f2bf(fmaxf(a[3]+bb[m].w, 0.f)) << 16);
          uint2 st; st.x = lo; st.y = hi;
          *(uint2*)(Xout + ((size_t)b*LSEQ + l)*OPAD + co) = st;
        }
      }
    }
  };

  stage(0, 0);
  __syncthreads();
  for (int t = 0; t < 8; ++t){
    if (t < 7) stage(t+1, (t+1)&1);
    compute(t, t&1);
    __syncthreads();
  }
}

// global max over l: X[b][l][128] -> z[b][128+c]
__global__ __launch_bounds__(256) void k_maxpool2(const u16* __restrict__ X, float* __restrict__ z){
  __shared__ float red[256][8];
  int b = blockIdx.x;
  int coct = threadIdx.x & 15, part = threadIdx.x >> 4;
  float m[8];
  #pragma unroll
  for (int j = 0; j < 8; ++j) m[j] = 0.f;   // post-ReLU values are >= 0
  const u16* Xb = X + (size_t)b*LSEQ*HID + coct*8;
  for (int l = part; l < LSEQ; l += 16){
    uint4 v = *(const uint4*)(Xb + (size_t)l*HID);
    u32 w[4] = {v.x, v.y, v.z, v.w};
    #pragma unroll
    for (int j = 0; j < 4; ++j){
      m[2*j]   = fmaxf(m[2*j],   bf2f(w[j] & 0xffffu));
      m[2*j+1] = fmaxf(m[2*j+1], bf2f(w[j] >> 16));
    }
  }
  #pragma unroll
  for (int j = 0; j < 8; ++j) red[threadIdx.x][j] = m[j];
  __syncthreads();
  if (threadIdx.x < 16){
    int c = threadIdx.x;
    float mm[8];
    #pragma unroll
    for (int j = 0; j < 8; ++j) mm[j] = red[c][j];
    for (int p = 1; p < 16; ++p)
      #pragma unroll
      for (int j = 0; j < 8; ++j) mm[j] = fmaxf(mm[j], red[p*16 + c][j]);
    for (int j = 0; j < 8; ++j) z[(size_t)b*(2*HID) + HID + c*8 + j] = mm[j];
  }
}

__global__ void k_head(const float* __restrict__ z2, const float* __restrict__ Wf2,
                       const float* __restrict__ bf2v, float* __restrict__ out){
  int b = blockIdx.x, lane = threadIdx.x;
  float s = 0.f;
  for (int k = lane; k < 2*HID; k += 64) s += z2[(size_t)b*(2*HID) + k] * Wf2[k];
  for (int o = 32; o; o >>= 1) s += __shfl_xor(s, o);
  if (lane == 0) out[b] = 1.f / (1.f + __expf(-(s + bf2v[0])));
}

extern "C" void kernel_launch(void* const* d_in, const int* in_sizes, int n_in,
                              void* d_out, int out_size, void* d_ws, size_t ws_size,
                              hipStream_t stream){
  const float* nf   = (const float*)d_in[0];
  const float* W_gc = (const float*)d_in[1];
  const float* b_gc = (const float*)d_in[2];
  const float* W_ri = (const float*)d_in[3];
  const float* b_ri = (const float*)d_in[4];
  const float* W_ro = (const float*)d_in[5];
  const float* b_ro = (const float*)d_in[6];
  const float* Wc1  = (const float*)d_in[7];
  const float* bc1  = (const float*)d_in[8];
  const float* Wc2  = (const float*)d_in[9];
  const float* bc2  = (const float*)d_in[10];
  const float* emb  = (const float*)d_in[11];
  const float* K1 = (const float*)d_in[12]; const float* cb1 = (const float*)d_in[13];
  const float* K2 = (const float*)d_in[14]; const float* cb2 = (const float*)d_in[15];
  const float* K3 = (const float*)d_in[16]; const float* cb3 = (const float*)d_in[17];
  const float* K4 = (const float*)d_in[18]; const float* cb4 = (const float*)d_in[19];
  const float* Wf1 = (const float*)d_in[20]; const float* bf1 = (const float*)d_in[21];
  const float* Wf2 = (const float*)d_in[22]; const float* bf2v = (const float*)d_in[23];
  const int* esrc = (const int*)d_in[24];
  const int* edst = (const int*)d_in[25];
  const int* gids = (const int*)d_in[26];
  const int* seq  = (const int*)d_in[27];
  float* out = (float*)d_out;

  int N = in_sizes[26];
  int E = in_sizes[24];
  int B = out_size;

  char* ws = (char*)d_ws;
  size_t off = 0;
  auto take = [&](size_t bytes)->char*{
    char* p = ws + off; off = (off + bytes + 255) & ~(size_t)255; return p;
  };
  float* rs_out = (float*)take((size_t)N*4);
  float* rs_in  = (float*)take((size_t)N*4);
  float* S    = (float*)take((size_t)B*HID*4);
  float* cnt  = (float*)take((size_t)B*4);
  float* T    = (float*)take((size_t)B*HID*4);
  float* hg   = (float*)take((size_t)B*HID*4);
  float* cv1  = (float*)take((size_t)B*HID*4);
  float* z    = (float*)take((size_t)B*2*HID*4);
  float* z2   = (float*)take((size_t)B*2*HID*4);
  u16* Ap1 = (u16*)take((size_t)96*384*2);  float* bp1 = (float*)take(96*4);
  u16* Ap2 = (u16*)take((size_t)128*288*2); float* bp2 = (float*)take(128*4);
  u16* Ap3 = (u16*)take((size_t)96*384*2);  float* bp3 = (float*)take(96*4);
  u16* Ap4 = (u16*)take((size_t)128*288*2); float* bp4 = (float*)take(128*4);
  u16* zbuf = (u16*)take(256);
  size_t bigoff = off;
  u16* XA = (u16*)take((size_t)B*LSEQ*128*2);   // 131 MB, 128-wide activations
  u16* XB = (u16*)take((size_t)B*LSEQ*96*2);    // 98 MB, 96-wide activations
  // graph scratch overlaps XA (graph branch completes before embed writes)
  float* h_agg = (float*)(ws + bigoff);
  float* h     = (float*)(ws + bigoff + (size_t)N*IN_DIM*4);

  // ---- graph branch ----
  k_deg_init <<<(N+255)/256, 256, 0, stream>>>(rs_out, rs_in, N);
  k_deg_edge <<<(E+255)/256, 256, 0, stream>>>(esrc, edst, rs_out, rs_in, E);
  k_deg_rsqrt<<<(N+255)/256, 256, 0, stream>>>(rs_out, rs_in, N);
  int tot74 = N * IN_DIM;
  k_init_hagg<<<(tot74+255)/256, 256, 0, stream>>>(nf, rs_out, h_agg, tot74);
  long long escat = (long long)E * 128;
  k_edge_scatter<<<(unsigned)((escat+255)/256), 256, 0, stream>>>(esrc, edst, nf, rs_out, h_agg, E);
  k_gc_gemm<<<N/8, 256, 0, stream>>>(h_agg, rs_in, W_gc, b_gc, h, N);
  k_segsum <<<B, HID, 0, stream>>>(h, gids, S, cnt, N);
  k_gemm_small<<<B, HID, 0, stream>>>(S,   HID, W_ri, b_ri, cnt,     T,   HID,   HID, 0);
  k_gemm_small<<<B, HID, 0, stream>>>(T,   HID, W_ro, b_ro, cnt,     hg,  HID,   HID, 1);
  k_gemm_small<<<B, HID, 0, stream>>>(hg,  HID, Wc1,  bc1,  nullptr, cv1, HID,   HID, 1);
  k_gemm_small<<<B, HID, 0, stream>>>(cv1, HID, Wc2,  bc2,  nullptr, z,   2*HID, HID, 1);

  // ---- protein branch ----
  k_zero<<<1, 64, 0, stream>>>((u32*)zbuf, 64);
  k_prepack<<<(96*384 +255)/256, 256, 0, stream>>>(K1, cb1, Ap1, bp1, 128, 128,  96,  96);
  k_prepack<<<(128*288+255)/256, 256, 0, stream>>>(K2, cb2, Ap2, bp2,  96,  96, 128, 128);
  k_prepack<<<(96*384 +255)/256, 256, 0, stream>>>(K3, cb3, Ap3, bp3, 128, 128,  74,  96);
  k_prepack<<<(128*288+255)/256, 256, 0, stream>>>(K4, cb4, Ap4, bp4,  74,  96, 128, 128);
  k_embed2<<<(512*LSEQ*16 + 255)/256, 256, 0, stream>>>(seq, emb, XA);
  k_conv_batch<128, 96><<<B, 256, 0, stream>>>(XA, Ap1, bp1, XB, zbuf);
  k_conv_batch< 96,128><<<B, 256, 0, stream>>>(XB, Ap2, bp2, XA, zbuf);
  k_conv_batch<128, 96><<<B, 256, 0, stream>>>(XA, Ap3, bp3, XB, zbuf);
  k_conv_batch< 96,128><<<B, 256, 0, stream>>>(XB, Ap4, bp4, XA, zbuf);
  k_maxpool2<<<B, 256, 0, stream>>>(XA, z);

  // ---- head ----
  k_gemm_small<<<B, 2*HID, 0, stream>>>(z, 2*HID, Wf1, bf1, nullptr, z2, 2*HID, 2*HID, 1);
  k_head<<<B, 64, 0, stream>>>(z2, Wf2, bf2v, out);
}

// Round 4
// 795.199 us; speedup vs baseline: 4.5007x; 1.0493x over previous
//
#include <hip/hip_runtime.h>
#include <math.h>

#define IN_DIM 74
#define HID 128
#define LSEQ 1000
#define RSA 272   // 128-ch LDS row bytes (17 x 16B slots, last = pad)
#define RSB 208   // 96-ch LDS row bytes (13 slots, last = pad)

typedef unsigned int u32;
typedef unsigned short u16;

typedef __attribute__((ext_vector_type(8))) short bf16x8;
typedef __attribute__((ext_vector_type(4))) float f32x4;

__device__ __forceinline__ float bf2f(u32 lo16){ return __uint_as_float(lo16 << 16); }
__device__ __forceinline__ u16 f2bf(float f){
  u32 u = __float_as_uint(f);
  u32 r = (u + 0x7fffu + ((u >> 16) & 1u)) >> 16;   // round-nearest-even
  return (u16)r;
}
__device__ __forceinline__ u32 pack2(float x, float y){
  return (u32)f2bf(x) | ((u32)f2bf(y) << 16);
}

// ---------- graph branch ----------
__global__ void k_deg_init(float* rs_out, float* rs_in, int N){
  int i = blockIdx.x*256 + threadIdx.x;
  if (i < N){ rs_out[i] = 1.f; rs_in[i] = 1.f; }   // self-loop counts as 1
}
__global__ void k_deg_edge(const int* __restrict__ src, const int* __restrict__ dst,
                           float* rs_out, float* rs_in, int E){
  int e = blockIdx.x*256 + threadIdx.x;
  if (e < E){ atomicAdd(&rs_out[src[e]], 1.f); atomicAdd(&rs_in[dst[e]], 1.f); }
}
__global__ void k_deg_rsqrt(float* rs_out, float* rs_in, int N){
  int i = blockIdx.x*256 + threadIdx.x;
  if (i < N){ rs_out[i] = rsqrtf(rs_out[i]); rs_in[i] = rsqrtf(rs_in[i]); }
}
__global__ void k_init_hagg(const float* __restrict__ nf, const float* __restrict__ rs_out,
                            float* h_agg, int total){
  int idx = blockIdx.x*256 + threadIdx.x;
  if (idx < total) h_agg[idx] = nf[idx] * rs_out[idx / IN_DIM];
}
// 32 lanes per edge, f strided by 32 (74 = 32+32+10)
__global__ void k_edge_scatter(const int* __restrict__ src, const int* __restrict__ dst,
                               const float* __restrict__ nf, const float* __restrict__ rs_out,
                               float* h_agg, int E){
  int gid = blockIdx.x*256 + threadIdx.x;
  int e = gid >> 5, q = gid & 31;
  if (e >= E) return;
  int s = src[e], d = dst[e];
  float w = rs_out[s];
  const float* np = nf + (size_t)s*IN_DIM;
  float* hp = h_agg + (size_t)d*IN_DIM;
  #pragma unroll
  for (int f0 = 0; f0 < 96; f0 += 32){
    int f = f0 + q;
    if (f < IN_DIM) atomicAdd(&hp[f], np[f]*w);
  }
}
__global__ __launch_bounds__(256) void k_gc_gemm(const float* __restrict__ h_agg,
        const float* __restrict__ rs_in, const float* __restrict__ W,
        const float* __restrict__ bias, float* __restrict__ h, int N){
  __shared__ float Wl[IN_DIM*HID];
  __shared__ float rows[8][IN_DIM];
  int base = blockIdx.x * 8;
  for (int idx = threadIdx.x; idx < IN_DIM*HID; idx += 256) Wl[idx] = W[idx];
  for (int idx = threadIdx.x; idx < 8*IN_DIM; idx += 256){
    int r = idx / IN_DIM, k = idx - r*IN_DIM;
    rows[r][k] = h_agg[(size_t)(base+r)*IN_DIM + k] * rs_in[base+r];
  }
  __syncthreads();
  int c = threadIdx.x & 127, rh = threadIdx.x >> 7;
  float a0=0,a1=0,a2=0,a3=0;
  for (int k = 0; k < IN_DIM; ++k){
    float w = Wl[k*HID + c];
    a0 += rows[rh  ][k]*w; a1 += rows[rh+2][k]*w;
    a2 += rows[rh+4][k]*w; a3 += rows[rh+6][k]*w;
  }
  float bv = bias[c];
  h[(size_t)(base+rh  )*HID+c] = fmaxf(a0+bv,0.f);
  h[(size_t)(base+rh+2)*HID+c] = fmaxf(a1+bv,0.f);
  h[(size_t)(base+rh+4)*HID+c] = fmaxf(a2+bv,0.f);
  h[(size_t)(base+rh+6)*HID+c] = fmaxf(a3+bv,0.f);
}
__global__ void k_segsum(const float* __restrict__ h, const int* __restrict__ gid,
                         float* S, float* cnt, int N){
  __shared__ int bounds[2];
  int g = blockIdx.x;
  if (threadIdx.x < 2){
    int target = g + (int)threadIdx.x;
    int lo = 0, hi = N;
    while (lo < hi){ int mid = (lo+hi)>>1; if (gid[mid] < target) lo = mid+1; else hi = mid; }
    bounds[threadIdx.x] = lo;
  }
  __syncthreads();
  int lo = bounds[0], hi = bounds[1];
  int c = threadIdx.x;
  float s = 0.f;
  for (int i = lo; i < hi; ++i) s += h[(size_t)i*HID + c];
  S[(size_t)g*HID + c] = s;
  if (c == 0) cnt[g] = (float)(hi - lo);
}
__global__ void k_gemm_small(const float* __restrict__ A, int AS, const float* __restrict__ W,
                             const float* __restrict__ bias, const float* __restrict__ bscale,
                             float* __restrict__ out, int OS, int K, int act){
  __shared__ float arow[256];
  int r = blockIdx.x, c = threadIdx.x, C = blockDim.x;
  for (int k = c; k < K; k += C) arow[k] = A[(size_t)r*AS + k];
  __syncthreads();
  float s = 0.f;
  for (int k = 0; k < K; ++k) s += arow[k] * W[(size_t)k*C + c];
  s += bias[c] * (bscale ? bscale[r] : 1.f);
  if (act) s = fmaxf(s, 0.f);
  out[(size_t)r*OS + c] = s;
}

// ---------- protein branch (fused, channel-last, MFMA) ----------

__global__ void k_zero(u32* p, int n){ int i = blockIdx.x*64 + threadIdx.x; if (i < n) p[i] = 0; }
__global__ void k_zero_zp(float* z, int total){   // zero z[:,128:256]
  int i = blockIdx.x*256 + threadIdx.x;
  if (i < total){ int b = i >> 7, c = i & 127; z[(size_t)b*256 + 128 + c] = 0.f; }
}

// prepack weights: Apack[co][k], k = t*CPAD + ci (bf16, zero-padded); bpad[co]
__global__ void k_prepack(const float* __restrict__ Kw, const float* __restrict__ bsrc,
                          u16* __restrict__ Apack, float* __restrict__ bpad,
                          int CIN, int CPAD, int COUT, int OPAD){
  int K = 3*CPAD;
  int idx = blockIdx.x*256 + threadIdx.x;
  if (idx < OPAD*K){
    int co = idx / K, k = idx - co*K;
    int t = k / CPAD, ci = k - t*CPAD;
    float v = (co < COUT && ci < CIN) ? Kw[((size_t)co*CIN + ci)*3 + t] : 0.f;
    Apack[idx] = f2bf(v);
  }
  if (idx < OPAD) bpad[idx] = (idx < COUT) ? bsrc[idx] : 0.f;
}

// 128ch-in -> 96ch-out layer: reads ldsA (RSA rows, in-row r = out-row r + tap),
// writes 66 out rows to ldsB as bf16 (OOB-l rows stored as 0 = conv zero-pad).
template<int NF>
__device__ __forceinline__ void layer_128_96(const char* ldsA, char* ldsB,
    const u16* __restrict__ Ap, const float* __restrict__ bp,
    int F0, int co0, int lm, int cg, int l0)
{
  bf16x8 Areg[36];
  #pragma unroll
  for (int ks = 0; ks < 12; ++ks)
    #pragma unroll
    for (int m = 0; m < 3; ++m)
      Areg[ks*3+m] = *(const bf16x8*)(Ap + (size_t)(co0 + m*16 + lm)*384 + ks*32 + cg*8);
  float4 bb[3];
  #pragma unroll
  for (int m = 0; m < 3; ++m) bb[m] = *(const float4*)(bp + co0 + m*16 + cg*4);

  f32x4 acc[3][NF];
  #pragma unroll
  for (int m = 0; m < 3; ++m)
    #pragma unroll
    for (int n = 0; n < NF; ++n) acc[m][n] = (f32x4){0.f,0.f,0.f,0.f};

  #pragma unroll
  for (int ks = 0; ks < 12; ++ks){
    const int tap = ks >> 2, c16 = (ks & 3)*4 + cg;
    bf16x8 Bf[NF];
    #pragma unroll
    for (int n = 0; n < NF; ++n){
      int row = (F0+n)*16 + lm + tap;
      Bf[n] = *(const bf16x8*)(ldsA + row*RSA + c16*16);
    }
    #pragma unroll
    for (int m = 0; m < 3; ++m)
      #pragma unroll
      for (int n = 0; n < NF; ++n)
        acc[m][n] = __builtin_amdgcn_mfma_f32_16x16x32_bf16(Areg[ks*3+m], Bf[n], acc[m][n], 0, 0, 0);
  }

  #pragma unroll
  for (int m = 0; m < 3; ++m){
    int co = co0 + m*16 + cg*4;
    #pragma unroll
    for (int n = 0; n < NF; ++n){
      int r1 = (F0+n)*16 + lm;
      if (r1 < 66){
        int l = l0 - 1 + r1;
        u32 lo = 0, hi = 0;
        if ((unsigned)l < (unsigned)LSEQ){
          f32x4 a = acc[m][n];
          lo = pack2(fmaxf(a[0]+bb[m].x, 0.f), fmaxf(a[1]+bb[m].y, 0.f));
          hi = pack2(fmaxf(a[2]+bb[m].z, 0.f), fmaxf(a[3]+bb[m].w, 0.f));
        }
        uint2 st; st.x = lo; st.y = hi;
        *(uint2*)(ldsB + r1*RSB + co*2) = st;
      }
    }
  }
}

// 96ch-in -> 128ch-out core (K=288, KS=9), acc[4][2], out rows 0..63 (l = l0+r)
__device__ __forceinline__ void core_96_128(const char* ldsB,
    const u16* __restrict__ Ap, int co0, int wl, int lm, int cg,
    bf16x8 (&Areg)[36], f32x4 (&acc)[4][2])
{
  #pragma unroll
  for (int ks = 0; ks < 9; ++ks)
    #pragma unroll
    for (int m = 0; m < 4; ++m)
      Areg[ks*4+m] = *(const bf16x8*)(Ap + (size_t)(co0 + m*16 + lm)*288 + ks*32 + cg*8);
  #pragma unroll
  for (int m = 0; m < 4; ++m)
    #pragma unroll
    for (int n = 0; n < 2; ++n) acc[m][n] = (f32x4){0.f,0.f,0.f,0.f};
  #pragma unroll
  for (int ks = 0; ks < 9; ++ks){
    const int tap = ks/3, c16 = (ks - tap*3)*4 + cg;
    bf16x8 Bf[2];
    #pragma unroll
    for (int n = 0; n < 2; ++n){
      int row = (wl*2+n)*16 + lm + tap;
      Bf[n] = *(const bf16x8*)(ldsB + row*RSB + c16*16);
    }
    #pragma unroll
    for (int m = 0; m < 4; ++m)
      #pragma unroll
      for (int n = 0; n < 2; ++n)
        acc[m][n] = __builtin_amdgcn_mfma_f32_16x16x32_bf16(Areg[ks*4+m], Bf[n], acc[m][n], 0, 0, 0);
  }
}

// kernel A: embed-gather -> L1 -> L2 -> store X2[b][l][128]
__global__ __launch_bounds__(256) void k_protein_a(
    const int* __restrict__ seq, const float* __restrict__ emb,
    const u16* __restrict__ Ap1, const float* __restrict__ bp1,
    const u16* __restrict__ Ap2, const float* __restrict__ bp2,
    u16* __restrict__ X2)
{
  __shared__ __align__(16) char ldsA[82*RSA];   // X0 rows 0..67 staged (l = l0-2+r)
  __shared__ __align__(16) char ldsB[66*RSB];   // X1 rows (l = l0-1+r)
  const int tid = threadIdx.x;
  const int b = blockIdx.y;
  const int l0 = blockIdx.x * 64;

  for (int idx = tid; idx < 68*16; idx += 256){
    int r = idx >> 4, p = idx & 15;
    int l = l0 - 2 + r;
    uint4 st = make_uint4(0u,0u,0u,0u);
    if ((unsigned)l < (unsigned)LSEQ){
      int tok = seq[b*LSEQ + l];
      const float4* e = (const float4*)(emb + (size_t)tok*HID + p*8);
      float4 v0 = e[0], v1 = e[1];
      st.x = pack2(v0.x, v0.y); st.y = pack2(v0.z, v0.w);
      st.z = pack2(v1.x, v1.y); st.w = pack2(v1.z, v1.w);
    }
    *(uint4*)(ldsA + r*RSA + p*16) = st;
  }
  const int lane = tid & 63, wid = tid >> 6;
  const int lm = lane & 15, cg = lane >> 4;
  const int wr = wid >> 1, wl = wid & 1;
  __syncthreads();

  if (wl == 0) layer_128_96<2>(ldsA, ldsB, Ap1, bp1, 0, wr*48, lm, cg, l0);
  else         layer_128_96<3>(ldsA, ldsB, Ap1, bp1, 2, wr*48, lm, cg, l0);
  __syncthreads();

  bf16x8 Areg[36];
  f32x4 acc[4][2];
  const int co0 = wr*64;
  core_96_128(ldsB, Ap2, co0, wl, lm, cg, Areg, acc);
  float4 bb[4];
  #pragma unroll
  for (int m = 0; m < 4; ++m) bb[m] = *(const float4*)(bp2 + co0 + m*16 + cg*4);
  u16* xb = X2 + (size_t)b*LSEQ*HID;
  #pragma unroll
  for (int m = 0; m < 4; ++m){
    int co = co0 + m*16 + cg*4;
    #pragma unroll
    for (int n = 0; n < 2; ++n){
      int l = l0 + (wl*2+n)*16 + lm;
      if (l < LSEQ){
        f32x4 a = acc[m][n];
        uint2 st;
        st.x = pack2(fmaxf(a[0]+bb[m].x, 0.f), fmaxf(a[1]+bb[m].y, 0.f));
        st.y = pack2(fmaxf(a[2]+bb[m].z, 0.f), fmaxf(a[3]+bb[m].w, 0.f));
        *(uint2*)(xb + (size_t)l*HID + co) = st;
      }
    }
  }
}

// kernel B: load X2 -> L3 -> L4 -> maxpool -> atomicMax into z[:,128:256]
__global__ __launch_bounds__(256) void k_protein_b(
    const u16* __restrict__ X2,
    const u16* __restrict__ Ap3, const float* __restrict__ bp3,
    const u16* __restrict__ Ap4, const float* __restrict__ bp4,
    float* __restrict__ z, const u16* __restrict__ zbuf)
{
  __shared__ __align__(16) char ldsA[82*RSA];   // X2 rows 0..67 (l = l0-2+r)
  __shared__ __align__(16) char ldsB[66*RSB];   // X3 rows (l = l0-1+r)
  const int tid = threadIdx.x;
  const int lane = tid & 63, wid = tid >> 6;
  const int b = blockIdx.y;
  const int l0 = blockIdx.x * 64;

  // stage 68 rows x 17 slots (slot 16 = pad -> zbuf) via global_load_lds
  const char* xb = (const char*)(X2 + (size_t)b*LSEQ*HID);
  #pragma unroll
  for (int it = 0; it < 5; ++it){
    int s = it*256 + tid;
    if (s < 68*17){
      int r = s / 17, slot = s - r*17;
      int l = l0 - 2 + r;
      const char* g = (slot < 16 && (unsigned)l < (unsigned)LSEQ)
                      ? (xb + (size_t)l*256 + slot*16) : (const char*)zbuf;
      __builtin_amdgcn_global_load_lds(
          (const __attribute__((address_space(1))) unsigned*)g,
          (__attribute__((address_space(3))) unsigned*)(ldsA + it*4096 + wid*1024),
          16, 0, 0);
    }
  }
  const int lm = lane & 15, cg = lane >> 4;
  const int wr = wid >> 1, wl = wid & 1;
  __syncthreads();

  if (wl == 0) layer_128_96<2>(ldsA, ldsB, Ap3, bp3, 0, wr*48, lm, cg, l0);
  else         layer_128_96<3>(ldsA, ldsB, Ap3, bp3, 2, wr*48, lm, cg, l0);
  __syncthreads();

  bf16x8 Areg[36];
  f32x4 acc[4][2];
  const int co0 = wr*64;
  core_96_128(ldsB, Ap4, co0, wl, lm, cg, Areg, acc);
  float4 bb[4];
  #pragma unroll
  for (int m = 0; m < 4; ++m) bb[m] = *(const float4*)(bp4 + co0 + m*16 + cg*4);

  float mx[4][4];
  #pragma unroll
  for (int m = 0; m < 4; ++m)
    #pragma unroll
    for (int j = 0; j < 4; ++j) mx[m][j] = 0.f;
  #pragma unroll
  for (int m = 0; m < 4; ++m){
    const float* bv = (const float*)&bb[m];
    #pragma unroll
    for (int n = 0; n < 2; ++n){
      int l = l0 + (wl*2+n)*16 + lm;
      if (l < LSEQ){
        #pragma unroll
        for (int j = 0; j < 4; ++j)
          mx[m][j] = fmaxf(mx[m][j], fmaxf(acc[m][n][j] + bv[j], 0.f));
      }
    }
  }
  #pragma unroll
  for (int o = 1; o <= 8; o <<= 1)
    #pragma unroll
    for (int m = 0; m < 4; ++m)
      #pragma unroll
      for (int j = 0; j < 4; ++j)
        mx[m][j] = fmaxf(mx[m][j], __shfl_xor(mx[m][j], o));
  if (lm == 0){
    float* zrow = z + (size_t)b*256 + 128;
    #pragma unroll
    for (int m = 0; m < 4; ++m)
      #pragma unroll
      for (int j = 0; j < 4; ++j)
        atomicMax((u32*)(zrow + co0 + m*16 + cg*4 + j), __float_as_uint(mx[m][j]));
  }
}

__global__ void k_head(const float* __restrict__ z2, const float* __restrict__ Wf2,
                       const float* __restrict__ bf2v, float* __restrict__ out){
  int b = blockIdx.x, lane = threadIdx.x;
  float s = 0.f;
  for (int k = lane; k < 2*HID; k += 64) s += z2[(size_t)b*(2*HID) + k] * Wf2[k];
  for (int o = 32; o; o >>= 1) s += __shfl_xor(s, o);
  if (lane == 0) out[b] = 1.f / (1.f + __expf(-(s + bf2v[0])));
}

extern "C" void kernel_launch(void* const* d_in, const int* in_sizes, int n_in,
                              void* d_out, int out_size, void* d_ws, size_t ws_size,
                              hipStream_t stream){
  const float* nf   = (const float*)d_in[0];
  const float* W_gc = (const float*)d_in[1];
  const float* b_gc = (const float*)d_in[2];
  const float* W_ri = (const float*)d_in[3];
  const float* b_ri = (const float*)d_in[4];
  const float* W_ro = (const float*)d_in[5];
  const float* b_ro = (const float*)d_in[6];
  const float* Wc1  = (const float*)d_in[7];
  const float* bc1  = (const float*)d_in[8];
  const float* Wc2  = (const float*)d_in[9];
  const float* bc2  = (const float*)d_in[10];
  const float* emb  = (const float*)d_in[11];
  const float* K1 = (const float*)d_in[12]; const float* cb1 = (const float*)d_in[13];
  const float* K2 = (const float*)d_in[14]; const float* cb2 = (const float*)d_in[15];
  const float* K3 = (const float*)d_in[16]; const float* cb3 = (const float*)d_in[17];
  const float* K4 = (const float*)d_in[18]; const float* cb4 = (const float*)d_in[19];
  const float* Wf1 = (const float*)d_in[20]; const float* bf1 = (const float*)d_in[21];
  const float* Wf2 = (const float*)d_in[22]; const float* bf2v = (const float*)d_in[23];
  const int* esrc = (const int*)d_in[24];
  const int* edst = (const int*)d_in[25];
  const int* gids = (const int*)d_in[26];
  const int* seq  = (const int*)d_in[27];
  float* out = (float*)d_out;

  int N = in_sizes[26];
  int E = in_sizes[24];
  int B = out_size;

  char* ws = (char*)d_ws;
  size_t off = 0;
  auto take = [&](size_t bytes)->char*{
    char* p = ws + off; off = (off + bytes + 255) & ~(size_t)255; return p;
  };
  float* rs_out = (float*)take((size_t)N*4);
  float* rs_in  = (float*)take((size_t)N*4);
  float* S    = (float*)take((size_t)B*HID*4);
  float* cnt  = (float*)take((size_t)B*4);
  float* T    = (float*)take((size_t)B*HID*4);
  float* hg   = (float*)take((size_t)B*HID*4);
  float* cv1  = (float*)take((size_t)B*HID*4);
  float* z    = (float*)take((size_t)B*2*HID*4);
  float* z2   = (float*)take((size_t)B*2*HID*4);
  u16* Ap1 = (u16*)take((size_t)96*384*2);  float* bp1 = (float*)take(96*4);
  u16* Ap2 = (u16*)take((size_t)128*288*2); float* bp2 = (float*)take(128*4);
  u16* Ap3 = (u16*)take((size_t)96*384*2);  float* bp3 = (float*)take(96*4);
  u16* Ap4 = (u16*)take((size_t)128*288*2); float* bp4 = (float*)take(128*4);
  u16* zbuf = (u16*)take(256);
  size_t bigoff = off;
  u16* X2 = (u16*)take((size_t)B*LSEQ*HID*2);   // 131 MB
  // graph scratch overlaps X2 (graph branch completes before kernel A writes X2)
  float* h_agg = (float*)(ws + bigoff);
  float* h     = (float*)(ws + bigoff + (size_t)N*IN_DIM*4);

  // ---- graph branch ----
  k_deg_init <<<(N+255)/256, 256, 0, stream>>>(rs_out, rs_in, N);
  k_deg_edge <<<(E+255)/256, 256, 0, stream>>>(esrc, edst, rs_out, rs_in, E);
  k_deg_rsqrt<<<(N+255)/256, 256, 0, stream>>>(rs_out, rs_in, N);
  int tot74 = N * IN_DIM;
  k_init_hagg<<<(tot74+255)/256, 256, 0, stream>>>(nf, rs_out, h_agg, tot74);
  long long escat = (long long)E * 32;
  k_edge_scatter<<<(unsigned)((escat+255)/256), 256, 0, stream>>>(esrc, edst, nf, rs_out, h_agg, E);
  k_gc_gemm<<<N/8, 256, 0, stream>>>(h_agg, rs_in, W_gc, b_gc, h, N);
  k_segsum <<<B, HID, 0, stream>>>(h, gids, S, cnt, N);
  k_gemm_small<<<B, HID, 0, stream>>>(S,   HID, W_ri, b_ri, cnt,     T,   HID,   HID, 0);
  k_gemm_small<<<B, HID, 0, stream>>>(T,   HID, W_ro, b_ro, cnt,     hg,  HID,   HID, 1);
  k_gemm_small<<<B, HID, 0, stream>>>(hg,  HID, Wc1,  bc1,  nullptr, cv1, HID,   HID, 1);
  k_gemm_small<<<B, HID, 0, stream>>>(cv1, HID, Wc2,  bc2,  nullptr, z,   2*HID, HID, 1);

  // ---- protein branch ----
  k_zero<<<1, 64, 0, stream>>>((u32*)zbuf, 64);
  k_zero_zp<<<(B*HID+255)/256, 256, 0, stream>>>(z, B*HID);
  k_prepack<<<(96*384 +255)/256, 256, 0, stream>>>(K1, cb1, Ap1, bp1, 128, 128,  96,  96);
  k_prepack<<<(128*288+255)/256, 256, 0, stream>>>(K2, cb2, Ap2, bp2,  96,  96, 128, 128);
  k_prepack<<<(96*384 +255)/256, 256, 0, stream>>>(K3, cb3, Ap3, bp3, 128, 128,  74,  96);
  k_prepack<<<(128*288+255)/256, 256, 0, stream>>>(K4, cb4, Ap4, bp4,  74,  96, 128, 128);
  dim3 pgrid(16, B);
  k_protein_a<<<pgrid, 256, 0, stream>>>(seq, emb, Ap1, bp1, Ap2, bp2, X2);
  k_protein_b<<<pgrid, 256, 0, stream>>>(X2, Ap3, bp3, Ap4, bp4, z, zbuf);

  // ---- head ----
  k_gemm_small<<<B, 2*HID, 0, stream>>>(z, 2*HID, Wf1, bf1, nullptr, z2, 2*HID, 2*HID, 1);
  k_head<<<B, 64, 0, stream>>>(z2, Wf2, bf2v, out);
}

// Round 5
// 645.884 us; speedup vs baseline: 5.5412x; 1.2312x over previous
//
#include <hip/hip_runtime.h>
#include <math.h>

#define IN_DIM 74
#define HID 128
#define LSEQ 1000
#define RSA 272   // 128-ch LDS row bytes (17 x 16B slots, last = pad)
#define RSB 208   // 96-ch LDS row bytes (13 slots, last = pad)

typedef unsigned int u32;
typedef unsigned short u16;

typedef __attribute__((ext_vector_type(8))) short bf16x8;
typedef __attribute__((ext_vector_type(4))) float f32x4;

__device__ __forceinline__ u16 f2bf(float f){
  u32 u = __float_as_uint(f);
  u32 r = (u + 0x7fffu + ((u >> 16) & 1u)) >> 16;   // round-nearest-even
  return (u16)r;
}
__device__ __forceinline__ u32 pack2(float x, float y){
  return (u32)f2bf(x) | ((u32)f2bf(y) << 16);
}

// ---------- graph branch: degree count + CSR build + gather ----------
__global__ void k_deg_init(int* out_cnt, int* in_cnt, int N){
  int i = blockIdx.x*256 + threadIdx.x;
  if (i < N){ out_cnt[i] = 0; in_cnt[i] = 0; }
}
__global__ void k_cnt_edge(const int* __restrict__ src, const int* __restrict__ dst,
                           int* out_cnt, int* in_cnt, int E){
  int e = blockIdx.x*256 + threadIdx.x;
  if (e < E){ atomicAdd(&out_cnt[src[e]], 1); atomicAdd(&in_cnt[dst[e]], 1); }
}
__global__ void k_scan1(const int* __restrict__ cnt, int* pref, int* bsum, int N){
  __shared__ int buf[256];
  int t = threadIdx.x, i = blockIdx.x*256 + t;
  int v = (i < N) ? cnt[i] : 0;
  buf[t] = v; __syncthreads();
  for (int o = 1; o < 256; o <<= 1){
    int tv = (t >= o) ? buf[t-o] : 0;
    __syncthreads(); buf[t] += tv; __syncthreads();
  }
  if (i < N) pref[i] = buf[t] - v;      // exclusive within block
  if (t == 255) bsum[blockIdx.x] = buf[255];
}
__global__ void k_scan2(int* bsum, int nb){
  __shared__ int buf[1024];
  int t = threadIdx.x;
  int v = (t < nb) ? bsum[t] : 0;
  buf[t] = v; __syncthreads();
  for (int o = 1; o < 1024; o <<= 1){
    int tv = (t >= o) ? buf[t-o] : 0;
    __syncthreads(); buf[t] += tv; __syncthreads();
  }
  if (t < nb) bsum[t] = buf[t] - v;     // exclusive block offsets
}
__global__ void k_scan3(const int* __restrict__ pref, const int* __restrict__ bsum,
                        int* offs, int* cur, int N){
  int i = blockIdx.x*256 + threadIdx.x;
  if (i < N){ int o = pref[i] + bsum[blockIdx.x]; offs[i] = o; cur[i] = o; }
}
__global__ void k_csr_fill(const int* __restrict__ src, const int* __restrict__ dst,
                           int* cur, int* csr_src, int E){
  int e = blockIdx.x*256 + threadIdx.x;
  if (e < E){ int slot = atomicAdd(&cur[dst[e]], 1); csr_src[slot] = src[e]; }
}
// per-dst gather with both norms folded: h_agg[d] = rsqrt(din) * sum_s nf[s]*rsqrt(dout[s])
__global__ __launch_bounds__(256) void k_gather(const float* __restrict__ nf,
    const int* __restrict__ csr_src, const int* __restrict__ offs,
    const int* __restrict__ in_cnt, const int* __restrict__ out_cnt,
    float* __restrict__ h_agg, int N){
  int wid = threadIdx.x >> 6, lane = threadIdx.x & 63;
  int d = blockIdx.x*4 + wid;
  if (d >= N) return;
  int beg = offs[d], num = in_cnt[d];
  const float* row = nf + (size_t)d*IN_DIM;
  float ws = rsqrtf((float)out_cnt[d] + 1.f);
  float a0 = row[lane]*ws, a1 = 0.f;
  if (lane < IN_DIM-64) a1 = row[64+lane]*ws;
  for (int j = 0; j < num; ++j){
    int s = csr_src[beg + j];
    float w = rsqrtf((float)out_cnt[s] + 1.f);
    const float* rs = nf + (size_t)s*IN_DIM;
    a0 += rs[lane]*w;
    if (lane < IN_DIM-64) a1 += rs[64+lane]*w;
  }
  float sc = rsqrtf((float)num + 1.f);
  float* hp = h_agg + (size_t)d*IN_DIM;
  hp[lane] = a0*sc;
  if (lane < IN_DIM-64) hp[64+lane] = a1*sc;
}
// h = relu(h_agg @ W_gc + b_gc), 32 rows/block, transposed-LDS broadcast reads
__global__ __launch_bounds__(256) void k_gc_gemm(const float* __restrict__ h_agg,
        const float* __restrict__ W, const float* __restrict__ bias,
        float* __restrict__ h, int N){
  __shared__ float Wl[IN_DIM*HID];
  __shared__ float rowsT[IN_DIM][36];
  int base = blockIdx.x * 32;
  for (int idx = threadIdx.x; idx < IN_DIM*HID; idx += 256) Wl[idx] = W[idx];
  for (int idx = threadIdx.x; idx < 32*IN_DIM; idx += 256){
    int r = idx / IN_DIM, k = idx - r*IN_DIM;
    rowsT[k][r] = (base + r < N) ? h_agg[(size_t)(base+r)*IN_DIM + k] : 0.f;
  }
  __syncthreads();
  int c = threadIdx.x & 127, rh = threadIdx.x >> 7;
  float acc[16];
  #pragma unroll
  for (int i = 0; i < 16; ++i) acc[i] = 0.f;
  for (int k = 0; k < IN_DIM; ++k){
    float w = Wl[k*HID + c];
    const float4* rp = (const float4*)&rowsT[k][rh*16];
    float4 r0 = rp[0], r1 = rp[1], r2 = rp[2], r3 = rp[3];
    acc[0] += r0.x*w; acc[1] += r0.y*w; acc[2] += r0.z*w; acc[3] += r0.w*w;
    acc[4] += r1.x*w; acc[5] += r1.y*w; acc[6] += r1.z*w; acc[7] += r1.w*w;
    acc[8] += r2.x*w; acc[9] += r2.y*w; acc[10] += r2.z*w; acc[11] += r2.w*w;
    acc[12] += r3.x*w; acc[13] += r3.y*w; acc[14] += r3.z*w; acc[15] += r3.w*w;
  }
  float bv = bias[c];
  #pragma unroll
  for (int i = 0; i < 16; ++i){
    int r = base + rh*16 + i;
    if (r < N) h[(size_t)r*HID + c] = fmaxf(acc[i] + bv, 0.f);
  }
}
// segsum + readout(2 linears) + compound FC(2 linears) -> z[:,0:128]
__global__ __launch_bounds__(128) void k_graph_tail(const float* __restrict__ h,
    const int* __restrict__ gid,
    const float* __restrict__ W_ri, const float* __restrict__ b_ri,
    const float* __restrict__ W_ro, const float* __restrict__ b_ro,
    const float* __restrict__ Wc1, const float* __restrict__ bc1,
    const float* __restrict__ Wc2, const float* __restrict__ bc2,
    float* __restrict__ z, int N){
  __shared__ float va[128], vb[128];
  __shared__ int bounds[2];
  int g = blockIdx.x, c = threadIdx.x;
  if (c < 2){
    int target = g + c, lo = 0, hi = N;
    while (lo < hi){ int mid = (lo+hi)>>1; if (gid[mid] < target) lo = mid+1; else hi = mid; }
    bounds[c] = lo;
  }
  __syncthreads();
  int lo = bounds[0], hi = bounds[1];
  float s = 0.f;
  for (int i = lo; i < hi; ++i) s += h[(size_t)i*HID + c];
  va[c] = s;
  float cn = (float)(hi - lo);
  __syncthreads();
  s = 0.f;
  for (int k = 0; k < 128; ++k) s += va[k]*W_ri[k*128 + c];
  vb[c] = s + b_ri[c]*cn;
  __syncthreads();
  s = 0.f;
  for (int k = 0; k < 128; ++k) s += vb[k]*W_ro[k*128 + c];
  va[c] = fmaxf(s + b_ro[c]*cn, 0.f);
  __syncthreads();
  s = 0.f;
  for (int k = 0; k < 128; ++k) s += va[k]*Wc1[k*128 + c];
  vb[c] = fmaxf(s + bc1[c], 0.f);
  __syncthreads();
  s = 0.f;
  for (int k = 0; k < 128; ++k) s += vb[k]*Wc2[k*128 + c];
  z[(size_t)g*256 + c] = fmaxf(s + bc2[c], 0.f);
}

// ---------- protein branch (single fused kernel) ----------
__global__ void k_zero_zp(float* z, int total){   // zero z[:,128:256]
  int i = blockIdx.x*256 + threadIdx.x;
  if (i < total){ int b = i >> 7, c = i & 127; z[(size_t)b*256 + 128 + c] = 0.f; }
}
__global__ void k_prepack(const float* __restrict__ Kw, const float* __restrict__ bsrc,
                          u16* __restrict__ Apack, float* __restrict__ bpad,
                          int CIN, int CPAD, int COUT, int OPAD){
  int K = 3*CPAD;
  int idx = blockIdx.x*256 + threadIdx.x;
  if (idx < OPAD*K){
    int co = idx / K, k = idx - co*K;
    int t = k / CPAD, ci = k - t*CPAD;
    float v = (co < COUT && ci < CIN) ? Kw[((size_t)co*CIN + ci)*3 + t] : 0.f;
    Apack[idx] = f2bf(v);
  }
  if (idx < OPAD) bpad[idx] = (idx < COUT) ? bsrc[idx] : 0.f;
}

// 128ch (ldsA) -> 96ch (ldsB); out row r1 <-> l = lbase+r1; in rows r1..r1+2
template<int NF>
__device__ __forceinline__ void layer_A2B(const char* ldsA, char* ldsB,
    const u16* __restrict__ Ap, const float* __restrict__ bp,
    int F0, int co0, int lm, int cg, int lbase, int nrows)
{
  bf16x8 Areg[36];
  #pragma unroll
  for (int ks = 0; ks < 12; ++ks)
    #pragma unroll
    for (int m = 0; m < 3; ++m)
      Areg[ks*3+m] = *(const bf16x8*)(Ap + (size_t)(co0 + m*16 + lm)*384 + ks*32 + cg*8);
  float4 bb[3];
  #pragma unroll
  for (int m = 0; m < 3; ++m) bb[m] = *(const float4*)(bp + co0 + m*16 + cg*4);

  f32x4 acc[3][NF];
  #pragma unroll
  for (int m = 0; m < 3; ++m)
    #pragma unroll
    for (int n = 0; n < NF; ++n) acc[m][n] = (f32x4){0.f,0.f,0.f,0.f};

  #pragma unroll
  for (int ks = 0; ks < 12; ++ks){
    const int tap = ks >> 2, c16 = (ks & 3)*4 + cg;
    bf16x8 Bf[NF];
    #pragma unroll
    for (int n = 0; n < NF; ++n){
      int row = (F0+n)*16 + lm + tap;
      Bf[n] = *(const bf16x8*)(ldsA + row*RSA + c16*16);
    }
    #pragma unroll
    for (int m = 0; m < 3; ++m)
      #pragma unroll
      for (int n = 0; n < NF; ++n)
        acc[m][n] = __builtin_amdgcn_mfma_f32_16x16x32_bf16(Areg[ks*3+m], Bf[n], acc[m][n], 0, 0, 0);
  }
  #pragma unroll
  for (int m = 0; m < 3; ++m){
    int co = co0 + m*16 + cg*4;
    #pragma unroll
    for (int n = 0; n < NF; ++n){
      int r1 = (F0+n)*16 + lm;
      if (r1 < nrows){
        int l = lbase + r1;
        u32 lo = 0, hi = 0;
        if ((unsigned)l < (unsigned)LSEQ){
          f32x4 a = acc[m][n];
          lo = pack2(fmaxf(a[0]+bb[m].x, 0.f), fmaxf(a[1]+bb[m].y, 0.f));
          hi = pack2(fmaxf(a[2]+bb[m].z, 0.f), fmaxf(a[3]+bb[m].w, 0.f));
        }
        uint2 st; st.x = lo; st.y = hi;
        *(uint2*)(ldsB + r1*RSB + co*2) = st;
      }
    }
  }
}

// 96ch (ldsB) -> 128ch (ldsA); same row relation
template<int NF>
__device__ __forceinline__ void layer_B2A(const char* ldsB, char* ldsA,
    const u16* __restrict__ Ap, const float* __restrict__ bp,
    int F0, int co0, int lm, int cg, int lbase, int nrows)
{
  bf16x8 Areg[36];
  #pragma unroll
  for (int ks = 0; ks < 9; ++ks)
    #pragma unroll
    for (int m = 0; m < 4; ++m)
      Areg[ks*4+m] = *(const bf16x8*)(Ap + (size_t)(co0 + m*16 + lm)*288 + ks*32 + cg*8);
  float4 bb[4];
  #pragma unroll
  for (int m = 0; m < 4; ++m) bb[m] = *(const float4*)(bp + co0 + m*16 + cg*4);

  f32x4 acc[4][NF];
  #pragma unroll
  for (int m = 0; m < 4; ++m)
    #pragma unroll
    for (int n = 0; n < NF; ++n) acc[m][n] = (f32x4){0.f,0.f,0.f,0.f};

  #pragma unroll
  for (int ks = 0; ks < 9; ++ks){
    const int tap = ks/3, c16 = (ks - tap*3)*4 + cg;
    bf16x8 Bf[NF];
    #pragma unroll
    for (int n = 0; n < NF; ++n){
      int row = (F0+n)*16 + lm + tap;
      Bf[n] = *(const bf16x8*)(ldsB + row*RSB + c16*16);
    }
    #pragma unroll
    for (int m = 0; m < 4; ++m)
      #pragma unroll
      for (int n = 0; n < NF; ++n)
        acc[m][n] = __builtin_amdgcn_mfma_f32_16x16x32_bf16(Areg[ks*4+m], Bf[n], acc[m][n], 0, 0, 0);
  }
  #pragma unroll
  for (int m = 0; m < 4; ++m){
    int co = co0 + m*16 + cg*4;
    #pragma unroll
    for (int n = 0; n < NF; ++n){
      int r1 = (F0+n)*16 + lm;
      if (r1 < nrows){
        int l = lbase + r1;
        u32 lo = 0, hi = 0;
        if ((unsigned)l < (unsigned)LSEQ){
          f32x4 a = acc[m][n];
          lo = pack2(fmaxf(a[0]+bb[m].x, 0.f), fmaxf(a[1]+bb[m].y, 0.f));
          hi = pack2(fmaxf(a[2]+bb[m].z, 0.f), fmaxf(a[3]+bb[m].w, 0.f));
        }
        uint2 st; st.x = lo; st.y = hi;
        *(uint2*)(ldsA + r1*RSA + co*2) = st;
      }
    }
  }
}

// final 96->128 layer + in-register maxpool + atomicMax into z[:,128:256]
__device__ __forceinline__ void layer_final(const char* ldsB,
    const u16* __restrict__ Ap, const float* __restrict__ bp,
    int co0, int wl, int lm, int cg, int l0, float* __restrict__ z, int b)
{
  const int F0 = wl*2;
  bf16x8 Areg[36];
  #pragma unroll
  for (int ks = 0; ks < 9; ++ks)
    #pragma unroll
    for (int m = 0; m < 4; ++m)
      Areg[ks*4+m] = *(const bf16x8*)(Ap + (size_t)(co0 + m*16 + lm)*288 + ks*32 + cg*8);
  float4 bb[4];
  #pragma unroll
  for (int m = 0; m < 4; ++m) bb[m] = *(const float4*)(bp + co0 + m*16 + cg*4);

  f32x4 acc[4][2];
  #pragma unroll
  for (int m = 0; m < 4; ++m){ acc[m][0] = (f32x4){0.f,0.f,0.f,0.f}; acc[m][1] = (f32x4){0.f,0.f,0.f,0.f}; }
  #pragma unroll
  for (int ks = 0; ks < 9; ++ks){
    const int tap = ks/3, c16 = (ks - tap*3)*4 + cg;
    bf16x8 Bf[2];
    #pragma unroll
    for (int n = 0; n < 2; ++n){
      int row = (F0+n)*16 + lm + tap;
      Bf[n] = *(const bf16x8*)(ldsB + row*RSB + c16*16);
    }
    #pragma unroll
    for (int m = 0; m < 4; ++m)
      #pragma unroll
      for (int n = 0; n < 2; ++n)
        acc[m][n] = __builtin_amdgcn_mfma_f32_16x16x32_bf16(Areg[ks*4+m], Bf[n], acc[m][n], 0, 0, 0);
  }
  float mx[4][4];
  #pragma unroll
  for (int m = 0; m < 4; ++m)
    #pragma unroll
    for (int j = 0; j < 4; ++j) mx[m][j] = 0.f;
  #pragma unroll
  for (int m = 0; m < 4; ++m){
    const float* bv = (const float*)&bb[m];
    #pragma unroll
    for (int n = 0; n < 2; ++n){
      int l = l0 + (F0+n)*16 + lm;
      if (l < LSEQ){
        #pragma unroll
        for (int j = 0; j < 4; ++j)
          mx[m][j] = fmaxf(mx[m][j], fmaxf(acc[m][n][j] + bv[j], 0.f));
      }
    }
  }
  #pragma unroll
  for (int o = 1; o <= 8; o <<= 1)
    #pragma unroll
    for (int m = 0; m < 4; ++m)
      #pragma unroll
      for (int j = 0; j < 4; ++j)
        mx[m][j] = fmaxf(mx[m][j], __shfl_xor(mx[m][j], o));
  if (lm == 0){
    float* zrow = z + (size_t)b*256 + 128;
    #pragma unroll
    for (int m = 0; m < 4; ++m)
      #pragma unroll
      for (int j = 0; j < 4; ++j)
        atomicMax((u32*)(zrow + co0 + m*16 + cg*4 + j), __float_as_uint(mx[m][j]));
  }
}

__global__ __launch_bounds__(256, 4) void k_protein(
    const int* __restrict__ seq, const float* __restrict__ emb,
    const u16* __restrict__ Ap1, const float* __restrict__ bp1,
    const u16* __restrict__ Ap2, const float* __restrict__ bp2,
    const u16* __restrict__ Ap3, const float* __restrict__ bp3,
    const u16* __restrict__ Ap4, const float* __restrict__ bp4,
    float* __restrict__ z)
{
  __shared__ __align__(16) char ldsA[82*RSA];   // 128-ch buffer (X0 / X2)
  __shared__ __align__(16) char ldsB[82*RSB];   // 96-ch buffer (X1 / X3)
  const int tid = threadIdx.x;
  const int b = blockIdx.y;
  const int l0 = blockIdx.x * 64;

  // embed: X0 rows 0..71, l = l0-4+r
  for (int idx = tid; idx < 72*16; idx += 256){
    int r = idx >> 4, p = idx & 15;
    int l = l0 - 4 + r;
    uint4 st = make_uint4(0u,0u,0u,0u);
    if ((unsigned)l < (unsigned)LSEQ){
      int tok = seq[b*LSEQ + l];
      const float4* e = (const float4*)(emb + (size_t)tok*HID + p*8);
      float4 v0 = e[0], v1 = e[1];
      st.x = pack2(v0.x, v0.y); st.y = pack2(v0.z, v0.w);
      st.z = pack2(v1.x, v1.y); st.w = pack2(v1.z, v1.w);
    }
    *(uint4*)(ldsA + r*RSA + p*16) = st;
  }
  const int lane = tid & 63, wid = tid >> 6;
  const int lm = lane & 15, cg = lane >> 4;
  const int wr = wid >> 1, wl = wid & 1;
  __syncthreads();

  // L1: X0(128) -> X1(96), l = (l0-3)+r, 70 rows
  if (wl == 0) layer_A2B<2>(ldsA, ldsB, Ap1, bp1, 0, wr*48, lm, cg, l0-3, 70);
  else         layer_A2B<3>(ldsA, ldsB, Ap1, bp1, 2, wr*48, lm, cg, l0-3, 70);
  __syncthreads();
  // L2: X1(96) -> X2(128), l = (l0-2)+r, 68 rows
  if (wl == 0) layer_B2A<2>(ldsB, ldsA, Ap2, bp2, 0, wr*64, lm, cg, l0-2, 68);
  else         layer_B2A<3>(ldsB, ldsA, Ap2, bp2, 2, wr*64, lm, cg, l0-2, 68);
  __syncthreads();
  // L3: X2(128) -> X3(96), l = (l0-1)+r, 66 rows
  if (wl == 0) layer_A2B<2>(ldsA, ldsB, Ap3, bp3, 0, wr*48, lm, cg, l0-1, 66);
  else         layer_A2B<3>(ldsA, ldsB, Ap3, bp3, 2, wr*48, lm, cg, l0-1, 66);
  __syncthreads();
  // L4: X3(96) -> maxpool
  layer_final(ldsB, Ap4, bp4, wr*64, wl, lm, cg, l0, z, b);
}

// head: relu(z@Wf1+bf1) @ Wf2 + bf2 -> sigmoid
__global__ __launch_bounds__(256) void k_fc_head(const float* __restrict__ z,
    const float* __restrict__ Wf1, const float* __restrict__ bf1,
    const float* __restrict__ Wf2, const float* __restrict__ bf2v,
    float* __restrict__ out){
  __shared__ float za[256];
  __shared__ float red[4];
  int r = blockIdx.x, c = threadIdx.x;
  za[c] = z[(size_t)r*256 + c];
  __syncthreads();
  float s = 0.f;
  for (int k = 0; k < 256; ++k) s += za[k]*Wf1[(size_t)k*256 + c];
  s = fmaxf(s + bf1[c], 0.f);
  float p = s * Wf2[c];
  for (int o = 32; o; o >>= 1) p += __shfl_xor(p, o);
  if ((c & 63) == 0) red[c >> 6] = p;
  __syncthreads();
  if (c == 0) out[r] = 1.f/(1.f + __expf(-(red[0]+red[1]+red[2]+red[3] + bf2v[0])));
}

extern "C" void kernel_launch(void* const* d_in, const int* in_sizes, int n_in,
                              void* d_out, int out_size, void* d_ws, size_t ws_size,
                              hipStream_t stream){
  const float* nf   = (const float*)d_in[0];
  const float* W_gc = (const float*)d_in[1];
  const float* b_gc = (const float*)d_in[2];
  const float* W_ri = (const float*)d_in[3];
  const float* b_ri = (const float*)d_in[4];
  const float* W_ro = (const float*)d_in[5];
  const float* b_ro = (const float*)d_in[6];
  const float* Wc1  = (const float*)d_in[7];
  const float* bc1  = (const float*)d_in[8];
  const float* Wc2  = (const float*)d_in[9];
  const float* bc2  = (const float*)d_in[10];
  const float* emb  = (const float*)d_in[11];
  const float* K1 = (const float*)d_in[12]; const float* cb1 = (const float*)d_in[13];
  const float* K2 = (const float*)d_in[14]; const float* cb2 = (const float*)d_in[15];
  const float* K3 = (const float*)d_in[16]; const float* cb3 = (const float*)d_in[17];
  const float* K4 = (const float*)d_in[18]; const float* cb4 = (const float*)d_in[19];
  const float* Wf1 = (const float*)d_in[20]; const float* bf1 = (const float*)d_in[21];
  const float* Wf2 = (const float*)d_in[22]; const float* bf2v = (const float*)d_in[23];
  const int* esrc = (const int*)d_in[24];
  const int* edst = (const int*)d_in[25];
  const int* gids = (const int*)d_in[26];
  const int* seq  = (const int*)d_in[27];
  float* out = (float*)d_out;

  int N = in_sizes[26];
  int E = in_sizes[24];
  int B = out_size;
  int nb = (N + 255)/256;

  char* ws = (char*)d_ws;
  size_t off = 0;
  auto take = [&](size_t bytes)->char*{
    char* p = ws + off; off = (off + bytes + 255) & ~(size_t)255; return p;
  };
  float* z      = (float*)take((size_t)B*2*HID*4);
  int* out_cnt  = (int*)take((size_t)N*4);
  int* in_cnt   = (int*)take((size_t)N*4);
  int* pref     = (int*)take((size_t)N*4);
  int* offs     = (int*)take((size_t)N*4);
  int* cur      = (int*)take((size_t)N*4);
  int* bsum     = (int*)take(1024*4);
  int* csr_src  = (int*)take((size_t)E*4);
  u16* Ap1 = (u16*)take((size_t)96*384*2);  float* bp1 = (float*)take(96*4);
  u16* Ap2 = (u16*)take((size_t)128*288*2); float* bp2 = (float*)take(128*4);
  u16* Ap3 = (u16*)take((size_t)96*384*2);  float* bp3 = (float*)take(96*4);
  u16* Ap4 = (u16*)take((size_t)128*288*2); float* bp4 = (float*)take(128*4);
  float* h_agg = (float*)take((size_t)N*IN_DIM*4);
  float* h     = (float*)take((size_t)N*HID*4);

  // ---- tiny setup ----
  k_zero_zp<<<(B*HID + 255)/256, 256, 0, stream>>>(z, B*HID);
  k_prepack<<<(96*384 +255)/256, 256, 0, stream>>>(K1, cb1, Ap1, bp1, 128, 128,  96,  96);
  k_prepack<<<(128*288+255)/256, 256, 0, stream>>>(K2, cb2, Ap2, bp2,  96,  96, 128, 128);
  k_prepack<<<(96*384 +255)/256, 256, 0, stream>>>(K3, cb3, Ap3, bp3, 128, 128,  74,  96);
  k_prepack<<<(128*288+255)/256, 256, 0, stream>>>(K4, cb4, Ap4, bp4,  74,  96, 128, 128);

  // ---- graph branch ----
  k_deg_init<<<nb, 256, 0, stream>>>(out_cnt, in_cnt, N);
  k_cnt_edge<<<(E+255)/256, 256, 0, stream>>>(esrc, edst, out_cnt, in_cnt, E);
  k_scan1<<<nb, 256, 0, stream>>>(in_cnt, pref, bsum, N);
  k_scan2<<<1, 1024, 0, stream>>>(bsum, nb);
  k_scan3<<<nb, 256, 0, stream>>>(pref, bsum, offs, cur, N);
  k_csr_fill<<<(E+255)/256, 256, 0, stream>>>(esrc, edst, cur, csr_src, E);
  k_gather<<<(N+3)/4, 256, 0, stream>>>(nf, csr_src, offs, in_cnt, out_cnt, h_agg, N);
  k_gc_gemm<<<(N+31)/32, 256, 0, stream>>>(h_agg, W_gc, b_gc, h, N);
  k_graph_tail<<<B, 128, 0, stream>>>(h, gids, W_ri, b_ri, W_ro, b_ro,
                                      Wc1, bc1, Wc2, bc2, z, N);

  // ---- protein branch (single fused kernel) ----
  dim3 pgrid(16, B);
  k_protein<<<pgrid, 256, 0, stream>>>(seq, emb, Ap1, bp1, Ap2, bp2, Ap3, bp3, Ap4, bp4, z);

  // ---- head ----
  k_fc_head<<<B, 256, 0, stream>>>(z, Wf1, bf1, Wf2, bf2v, out);
}